// Round 21
// baseline (466.375 us; speedup 1.0000x reference)
//
#include <hip/hip_runtime.h>
#include <hip/hip_bf16.h>
#include <hip/hip_fp8.h>
#include <math.h>

#define NITEMS 100000
#define NUSERS 16384
#define HLEN   48
#define GCN    128
#define ATTN_D 128
#define HID    256
#define TOW    256

typedef __attribute__((ext_vector_type(8))) short short8;
typedef __attribute__((ext_vector_type(16))) unsigned char uchar16;
typedef __attribute__((ext_vector_type(4))) float f32x4;
typedef __hip_bfloat16 bf16;

static __device__ __forceinline__ float bfu(unsigned short u) {
  unsigned int x = ((unsigned int)u) << 16;
  float f; __builtin_memcpy(&f, &x, 4); return f;
}
static __device__ __forceinline__ short f2bf(float v) {
  bf16 h = __float2bfloat16(v);
  short s; __builtin_memcpy(&s, &h, 2); return s;
}
static __device__ __forceinline__ unsigned char f2e4m3(float v) {
  __hip_fp8_e4m3 t(v);
  return (unsigned char)t.__x;
}
static __device__ __forceinline__ float e4m3f(unsigned char b) {
  __hip_fp8_e4m3 t;
  t.__x = (__hip_fp8_storage_t)b;
  return (float)t;
}

// global->LDS direct copy, 16B per lane; lds dest = wave-uniform base + lane*16
#define GLDS16(g, l)                                                            \
  __builtin_amdgcn_global_load_lds(                                             \
      (const __attribute__((address_space(1))) unsigned int*)(g),               \
      (__attribute__((address_space(3))) unsigned int*)(l), 16, 0, 0)

// ---------------------------------------------------------------------------
// Prep: pack fp32 weight [Korig][N] -> bf16 fragment-ordered buffer.
// perm=1: source row permuted gcn-first (srck = k<128 ? k+2 : k-128).
// ---------------------------------------------------------------------------
__global__ __launch_bounds__(256) void k_prep_w(const float* __restrict__ W,
                                                bf16* __restrict__ out,
                                                int Korig, int KS, int NT, int perm) {
  int tid = blockIdx.x * 256 + threadIdx.x;
  int total = KS * NT * 512;
  if (tid >= total) return;
  int i  = tid & 7;
  int l  = (tid >> 3) & 63;
  int ct = (tid >> 9) % NT;
  int ks = (tid >> 9) / NT;
  int k   = ks * 32 + ((l >> 4) << 3) + i;
  int col = ct * 16 + (l & 15);
  int N = NT * 16;
  int srck = perm ? ((k < 128) ? (k + 2) : (k - 128)) : k;
  float v = (k < Korig) ? W[(size_t)srck * N + col] : 0.f;
  out[tid] = __float2bfloat16(v);
}

__global__ __launch_bounds__(256) void k_prep_user(const float* __restrict__ gcn_user,
                                                   bf16* __restrict__ fused) {
  int tid = blockIdx.x * 256 + threadIdx.x;
  if (tid >= NUSERS * GCN) return;
  int k = tid & 127;
  int u = tid >> 7;
  fused[(size_t)u * (GCN + TOW) + k] = __float2bfloat16(gcn_user[tid]);
}

// ---------------------------------------------------------------------------
// Fold: Wqk[g][t] = (1/sqrt(128)) * sum_d Wq[g][d] * Wk[t][d]   (g<128)
//       b~[t]    = (1/sqrt(128)) * sum_d bq[d]    * Wk[t][d]    (block 16)
// ---------------------------------------------------------------------------
__global__ __launch_bounds__(256) void k_fold(const float* __restrict__ Wq,
                                              const float* __restrict__ Wk,
                                              const float* __restrict__ bq,
                                              float* __restrict__ out) {
  const float INV_S = 0.08838834764831845f;
  const int t = threadIdx.x;
  const int b = blockIdx.x;
  if (b < 16) {
    __shared__ float wq[8][128];
    for (int s = t; s < 8 * 128; s += 256)
      wq[s >> 7][s & 127] = Wq[(size_t)(b * 8 + (s >> 7)) * ATTN_D + (s & 127)];
    __syncthreads();
    float acc[8] = {0.f, 0.f, 0.f, 0.f, 0.f, 0.f, 0.f, 0.f};
    for (int d = 0; d < 128; ++d) {
      const float wk = Wk[(size_t)t * ATTN_D + d];
      #pragma unroll
      for (int gg = 0; gg < 8; ++gg) acc[gg] = fmaf(wq[gg][d], wk, acc[gg]);
    }
    #pragma unroll
    for (int gg = 0; gg < 8; ++gg)
      out[(size_t)(b * 8 + gg) * TOW + t] = acc[gg] * INV_S;
  } else {
    float a = 0.f;
    for (int d = 0; d < 128; ++d)
      a = fmaf(bq[d], Wk[(size_t)t * ATTN_D + d], a);
    out[(size_t)128 * TOW + t] = a * INV_S;
  }
}

// ---------------------------------------------------------------------------
// Item GEMM1 (fused cast), MR=1 + A-prefetch pipeline: h = relu(A@W1p + b1).
// 8 waves x 16 rows = 128-row tiles; A frags built in-register from fp32
// (RTNE bf16, identical rounding); next-ks A prefetched during MFMAs.
// Rows >= NITEMS clamped (pad outputs unused).
// ---------------------------------------------------------------------------
__global__ __launch_bounds__(512, 2) void k_item_g1(
    const float* __restrict__ feat,
    const float* __restrict__ gcn,
    const bf16* __restrict__ Wf,      // packed KS=5, NT=16, perm gcn-first
    const float* __restrict__ bias,
    bf16* __restrict__ h_out,
    int ntiles)
{
  __shared__ bf16 bs[5 * 8192];       // 80 KB = full W1p
  const int j = threadIdx.x;
  const int l = j & 63;
  const int w = j >> 6;               // 0..7 row-wave
  const int r = l & 15, g = l >> 4;
  const int jb = (j & ~63) * 8;

  #pragma unroll
  for (int s = 0; s < 10; ++s)
    GLDS16(Wf + (size_t)s * 4096 + (size_t)j * 8, &bs[s * 4096 + jb]);

  float bj[16];
  #pragma unroll
  for (int ct = 0; ct < 16; ++ct) bj[ct] = bias[ct * 16 + r];

  __syncthreads();   // only barrier

  for (int t = blockIdx.x; t < ntiles; t += gridDim.x) {
    const int R0 = t * 128 + w * 16;
    int row = R0 + r; if (row >= NITEMS) row = NITEMS - 1;
    const float* grow = gcn + (size_t)row * GCN;

    f32x4 acc[16];
    #pragma unroll
    for (int ct = 0; ct < 16; ++ct) acc[ct] = (f32x4){0.f, 0.f, 0.f, 0.f};

    const bf16* wbase = bs + (size_t)l * 8;

    // fp32 source double-buffer (A latency is the long pole here)
    float4 x0 = ((const float4*)(grow + g * 8))[0];
    float4 y0 = ((const float4*)(grow + g * 8))[1];
    float4 x1, y1;

    #pragma unroll
    for (int ks = 0; ks < 5; ++ks) {
      // prefetch next ks's fp32 source
      if (ks + 1 < 4) {
        x1 = ((const float4*)(grow + (ks + 1) * 32 + g * 8))[0];
        y1 = ((const float4*)(grow + (ks + 1) * 32 + g * 8))[1];
      }
      short8 a;
      if (ks < 4) {
        a[0] = f2bf(x0.x); a[1] = f2bf(x0.y); a[2] = f2bf(x0.z); a[3] = f2bf(x0.w);
        a[4] = f2bf(y0.x); a[5] = f2bf(y0.y); a[6] = f2bf(y0.z); a[7] = f2bf(y0.w);
      } else {
        a = (short8){0, 0, 0, 0, 0, 0, 0, 0};
        if (g == 0) {
          a[0] = f2bf(feat[(size_t)row * 2]);
          a[1] = f2bf(feat[(size_t)row * 2 + 1]);
        }
      }
      const bf16* wb = wbase + (size_t)(ks * 16) * 512;
      #pragma unroll
      for (int ct = 0; ct < 16; ++ct) {
        short8 b = *(const short8*)(wb + ct * 512);
        acc[ct] = __builtin_amdgcn_mfma_f32_16x16x32_bf16(a, b, acc[ct], 0, 0, 0);
      }
      x0 = x1; y0 = y1;
    }

    #pragma unroll
    for (int ct = 0; ct < 16; ++ct)
      #pragma unroll
      for (int i = 0; i < 4; ++i)
        h_out[(size_t)(R0 + g * 4 + i) * 256 + ct * 16 + r] =
            __float2bfloat16(fmaxf(acc[ct][i] + bj[ct], 0.f));
  }
}

// ---------------------------------------------------------------------------
// Persistent-B MFMA GEMM, MR=1 + full double-buffered fragment pipeline:
// while the 16 MFMAs of step ks run, ks+1's A (global) and 16 B-frags (LDS)
// are already in flight in registers. acc=64 AGPR + ~170 VGPR < 256 cap.
// 8 waves x 16 rows = 128-row tiles, barrier-free grind.
// MODE 0: relu->bf16.  MODE 1: l2norm->fp8 e4m3.
// ---------------------------------------------------------------------------
template<int KS, int MODE>
__global__ __launch_bounds__(512, 2) void k_gemm_pers(
    const bf16* __restrict__ A,
    const bf16* __restrict__ Wf,      // packed NT=16 fragment order
    const float* __restrict__ bias,
    void* __restrict__ Cout,
    int ntiles, int Astride)
{
  __shared__ bf16 bs[KS * 8192];      // KS * 16 KB = full B
  const int j = threadIdx.x;
  const int l = j & 63;
  const int w = j >> 6;               // 0..7 row-wave
  const int r = l & 15, g = l >> 4;
  const int jb = (j & ~63) * 8;

  #pragma unroll
  for (int s = 0; s < 2 * KS; ++s)
    GLDS16(Wf + (size_t)s * 4096 + (size_t)j * 8, &bs[s * 4096 + jb]);

  float bj[16];
  #pragma unroll
  for (int ct = 0; ct < 16; ++ct) bj[ct] = bias[ct * 16 + r];

  __syncthreads();   // only barrier

  for (int t = blockIdx.x; t < ntiles; t += gridDim.x) {
    const int R0 = t * 128 + w * 16;
    const bf16* arow = A + (size_t)(R0 + r) * Astride + g * 8;
    const bf16* wbase = bs + (size_t)l * 8;

    f32x4 acc[16];
    #pragma unroll
    for (int ct = 0; ct < 16; ++ct) acc[ct] = (f32x4){0.f, 0.f, 0.f, 0.f};

    short8 a0, a1, b0[16], b1[16];
    a0 = *(const short8*)(arow);
    #pragma unroll
    for (int ct = 0; ct < 16; ++ct)
      b0[ct] = *(const short8*)(wbase + (size_t)ct * 512);

    #pragma unroll
    for (int ks = 0; ks < KS; ks += 2) {
      if (ks + 1 < KS) {
        a1 = *(const short8*)(arow + (ks + 1) * 32);
        #pragma unroll
        for (int ct = 0; ct < 16; ++ct)
          b1[ct] = *(const short8*)(wbase + (size_t)((ks + 1) * 16 + ct) * 512);
      }
      #pragma unroll
      for (int ct = 0; ct < 16; ++ct)
        acc[ct] = __builtin_amdgcn_mfma_f32_16x16x32_bf16(a0, b0[ct], acc[ct], 0, 0, 0);
      if (ks + 2 < KS) {
        a0 = *(const short8*)(arow + (ks + 2) * 32);
        #pragma unroll
        for (int ct = 0; ct < 16; ++ct)
          b0[ct] = *(const short8*)(wbase + (size_t)((ks + 2) * 16 + ct) * 512);
      }
      if (ks + 1 < KS) {
        #pragma unroll
        for (int ct = 0; ct < 16; ++ct)
          acc[ct] = __builtin_amdgcn_mfma_f32_16x16x32_bf16(a1, b1[ct], acc[ct], 0, 0, 0);
      }
    }

    #pragma unroll
    for (int ct = 0; ct < 16; ++ct)
      #pragma unroll
      for (int i = 0; i < 4; ++i) acc[ct][i] += bj[ct];

    if (MODE == 0) {
      bf16* C = (bf16*)Cout;
      #pragma unroll
      for (int ct = 0; ct < 16; ++ct)
        #pragma unroll
        for (int i = 0; i < 4; ++i)
          C[(size_t)(R0 + g * 4 + i) * 256 + ct * 16 + r] =
              __float2bfloat16(fmaxf(acc[ct][i], 0.f));
    } else {
      unsigned char* C8 = (unsigned char*)Cout;
      float s[4] = {0.f, 0.f, 0.f, 0.f};
      #pragma unroll
      for (int ct = 0; ct < 16; ++ct)
        #pragma unroll
        for (int i = 0; i < 4; ++i) s[i] += acc[ct][i] * acc[ct][i];
      #pragma unroll
      for (int off = 1; off < 16; off <<= 1) {
        #pragma unroll
        for (int i = 0; i < 4; ++i) s[i] += __shfl_xor(s[i], off);
      }
      float rn[4];
      #pragma unroll
      for (int i = 0; i < 4; ++i) rn[i] = 1.f / fmaxf(sqrtf(s[i]), 1e-12f);
      #pragma unroll
      for (int ct = 0; ct < 16; ++ct)
        #pragma unroll
        for (int i = 0; i < 4; ++i)
          C8[(size_t)(R0 + g * 4 + i) * 256 + ct * 16 + r] =
              f2e4m3(acc[ct][i] * rn[i]);
    }
  }
}

// ---------------------------------------------------------------------------
// Generic MFMA GEMM (user tower), LDS-staged double-buffered B, 4 waves.
// MODE 0: relu->bf16; 3: l2norm->fp32; 4: plain->fp32
// ---------------------------------------------------------------------------
template<int KS, int NT, int MODE, int MR>
__global__ __launch_bounds__(256) void k_gemm(
    const bf16* __restrict__ A,
    const bf16* __restrict__ Wf,
    const float* __restrict__ bias,
    void* __restrict__ Cout,
    int Mtiles, int Astride)
{
  static_assert(NT % 4 == 0, "NT must be divisible by 4");
  constexpr int BSZ = NT * 512;
  constexpr int CH  = NT / 4;
  __shared__ bf16 bs[2][BSZ];
  const int j   = threadIdx.x;
  const int l   = j & 63;
  const int wid = j >> 6;
  int tile = blockIdx.x * 4 + wid;
  if (tile >= Mtiles) tile = Mtiles - 1;
  const int N = NT * 16;
  const int r = l & 15, g = l >> 4;

  {
    const short8* src = (const short8*)Wf;
    short8* dst = (short8*)bs[0];
    #pragma unroll
    for (int c = 0; c < CH; ++c) dst[c * 256 + j] = src[c * 256 + j];
  }

  f32x4 acc[MR][NT];
  #pragma unroll
  for (int mr = 0; mr < MR; ++mr)
    #pragma unroll
    for (int ct = 0; ct < NT; ++ct) acc[mr][ct] = (f32x4){0.f, 0.f, 0.f, 0.f};

  const bf16* arow[MR];
  #pragma unroll
  for (int mr = 0; mr < MR; ++mr)
    arow[mr] = A + (size_t)(tile * (16 * MR) + mr * 16 + r) * Astride + g * 8;

  __syncthreads();

  #pragma unroll
  for (int ks = 0; ks < KS; ++ks) {
    const int cur = ks & 1;
    short8 a[MR];
    #pragma unroll
    for (int mr = 0; mr < MR; ++mr) a[mr] = *(const short8*)(arow[mr] + ks * 32);
    short8 st[CH];
    if (ks + 1 < KS) {
      const short8* src = (const short8*)(Wf + (size_t)(ks + 1) * BSZ);
      #pragma unroll
      for (int c = 0; c < CH; ++c) st[c] = src[c * 256 + j];
    }
    const bf16* wb = bs[cur] + (size_t)l * 8;
    #pragma unroll
    for (int ct = 0; ct < NT; ++ct) {
      short8 b = *(const short8*)(wb + ct * 512);
      #pragma unroll
      for (int mr = 0; mr < MR; ++mr)
        acc[mr][ct] = __builtin_amdgcn_mfma_f32_16x16x32_bf16(a[mr], b, acc[mr][ct], 0, 0, 0);
    }
    if (ks + 1 < KS) {
      short8* dst = (short8*)bs[cur ^ 1];
      #pragma unroll
      for (int c = 0; c < CH; ++c) dst[c * 256 + j] = st[c];
    }
    __syncthreads();
  }

  #pragma unroll
  for (int mr = 0; mr < MR; ++mr) {
    #pragma unroll
    for (int ct = 0; ct < NT; ++ct) {
      const float bj = bias[ct * 16 + r];
      #pragma unroll
      for (int i = 0; i < 4; ++i) acc[mr][ct][i] += bj;
    }
  }

  if (MODE == 0 || MODE == 2 || MODE == 4) {
    #pragma unroll
    for (int mr = 0; mr < MR; ++mr)
      #pragma unroll
      for (int ct = 0; ct < NT; ++ct)
        #pragma unroll
        for (int i = 0; i < 4; ++i) {
          float v = acc[mr][ct][i];
          if (MODE == 0) v = fmaxf(v, 0.f);
          size_t off = (size_t)(tile * (16 * MR) + mr * 16 + g * 4 + i) * N + ct * 16 + r;
          if (MODE == 4) ((float*)Cout)[off] = v;
          else           ((bf16*)Cout)[off]  = __float2bfloat16(v);
        }
  } else {
    #pragma unroll
    for (int mr = 0; mr < MR; ++mr) {
      float s[4] = {0.f, 0.f, 0.f, 0.f};
      #pragma unroll
      for (int ct = 0; ct < NT; ++ct)
        #pragma unroll
        for (int i = 0; i < 4; ++i) s[i] += acc[mr][ct][i] * acc[mr][ct][i];
      #pragma unroll
      for (int off = 1; off < 16; off <<= 1) {
        #pragma unroll
        for (int i = 0; i < 4; ++i) s[i] += __shfl_xor(s[i], off);
      }
      float rn[4];
      #pragma unroll
      for (int i = 0; i < 4; ++i) rn[i] = 1.f / fmaxf(sqrtf(s[i]), 1e-12f);
      #pragma unroll
      for (int ct = 0; ct < NT; ++ct)
        #pragma unroll
        for (int i = 0; i < 4; ++i) {
          size_t off = (size_t)(tile * (16 * MR) + mr * 16 + g * 4 + i) * N + ct * 16 + r;
          float v = acc[mr][ct][i] * rn[i];
          if (MODE == 3) ((float*)Cout)[off] = v;
          else           ((bf16*)Cout)[off]  = __float2bfloat16(v);
        }
    }
  }
}

// ---------------------------------------------------------------------------
// Attention v7-fp8: 16-lane row groups, no-max softmax (|s|<0.1 by
// construction), fp8 e4m3 embeddings (one 16B load/lane/row).
// ---------------------------------------------------------------------------
__global__ __launch_bounds__(256) void k_user_attn(
    const float* __restrict__ Qt,          // [NUSERS][TOW] fp32 (Wqk-folded)
    const int*   __restrict__ hist_idx,
    const int*   __restrict__ hist_len,
    const unsigned char* __restrict__ emb8,// [NPAD][TOW] fp8 e4m3 (normalized)
    bf16* __restrict__ fused)
{
  const int u = blockIdx.x;
  const int j = threadIdx.x;
  const int wid = j >> 6, lane = j & 63;
  const int g = lane >> 4, r = lane & 15;
  const int part = wid * 4 + g;
  __shared__ int   idx[HLEN];
  __shared__ float redO[16][TOW + 4];
  __shared__ float redL[16];

  const int nv = hist_len[u] + 1;

  if (j < HLEN) idx[j] = hist_idx[u * HLEN + j];
  const float* qp = Qt + (size_t)u * TOW + r * 16;
  f32x4 q0 = *(const f32x4*)(qp);
  f32x4 q1 = *(const f32x4*)(qp + 4);
  f32x4 q2 = *(const f32x4*)(qp + 8);
  f32x4 q3 = *(const f32x4*)(qp + 12);
  __syncthreads();

  float l = 0.f;
  f32x4 O0 = (f32x4){0.f,0.f,0.f,0.f}, O1 = O0, O2 = O0, O3 = O0;

  for (int h = part; h < nv; h += 16) {
    const uchar16 e = *(const uchar16*)(emb8 + (size_t)idx[h] * TOW + r * 16);
    float ef[16];
    #pragma unroll
    for (int i = 0; i < 16; ++i) ef[i] = e4m3f(e[i]);

    float sc = q0.x*ef[0] + q0.y*ef[1] + q0.z*ef[2] + q0.w*ef[3]
             + q1.x*ef[4] + q1.y*ef[5] + q1.z*ef[6] + q1.w*ef[7]
             + q2.x*ef[8] + q2.y*ef[9] + q2.z*ef[10]+ q2.w*ef[11]
             + q3.x*ef[12]+ q3.y*ef[13]+ q3.z*ef[14]+ q3.w*ef[15];
    #pragma unroll
    for (int off = 1; off < 16; off <<= 1) sc += __shfl_xor(sc, off);
    const float p = __expf(sc);
    l += p;
    O0.x += p*ef[0];  O0.y += p*ef[1];  O0.z += p*ef[2];  O0.w += p*ef[3];
    O1.x += p*ef[4];  O1.y += p*ef[5];  O1.z += p*ef[6];  O1.w += p*ef[7];
    O2.x += p*ef[8];  O2.y += p*ef[9];  O2.z += p*ef[10]; O2.w += p*ef[11];
    O3.x += p*ef[12]; O3.y += p*ef[13]; O3.z += p*ef[14]; O3.w += p*ef[15];
  }

  *(f32x4*)(&redO[part][r * 16])      = O0;
  *(f32x4*)(&redO[part][r * 16 + 4])  = O1;
  *(f32x4*)(&redO[part][r * 16 + 8])  = O2;
  *(f32x4*)(&redO[part][r * 16 + 12]) = O3;
  if (r == 0) redL[part] = l;
  __syncthreads();

  float L = 0.f, val = 0.f;
  #pragma unroll
  for (int w = 0; w < 16; ++w) {
    L   += redL[w];
    val += redO[w][j];
  }
  fused[(size_t)u * (GCN + TOW) + GCN + j] = __float2bfloat16(val / L);
}

// ---------------------------------------------------------------------------
extern "C" void kernel_launch(void* const* d_in, const int* in_sizes, int n_in,
                              void* d_out, int out_size, void* d_ws, size_t ws_size,
                              hipStream_t stream) {
  const float* item_feat = (const float*)d_in[0];
  const float* gcn_item  = (const float*)d_in[1];
  const float* gcn_user  = (const float*)d_in[2];
  const int*   hist_idx  = (const int*)d_in[3];
  const int*   hist_len  = (const int*)d_in[4];
  const float* Wi1 = (const float*)d_in[5];
  const float* bi1 = (const float*)d_in[6];
  const float* Wi2 = (const float*)d_in[7];
  const float* bi2 = (const float*)d_in[8];
  const float* Wq  = (const float*)d_in[9];
  const float* bq  = (const float*)d_in[10];
  const float* Wk  = (const float*)d_in[11];
  const float* bk  = (const float*)d_in[12];  // cancels in softmax
  const float* Wu1 = (const float*)d_in[13];
  const float* bu1 = (const float*)d_in[14];
  const float* Wu2 = (const float*)d_in[15];
  const float* bu2 = (const float*)d_in[16];
  (void)bk;

  char* ws = (char*)d_ws;
  bf16*  Wi1p  = (bf16*)(ws + 0);            // 81,920 B
  bf16*  Wi2p  = (bf16*)(ws + 81920);        // -> 212,992
  bf16*  Wu1p  = (bf16*)(ws + 212992);       // -> 409,600
  bf16*  Wu2p  = (bf16*)(ws + 409600);       // -> 540,672
  float* Wqkf  = (float*)(ws + 540672);      // -> 672,768
  bf16*  Wqkp  = (bf16*)(ws + 672768);       // -> 738,304
  float* Qt    = (float*)(ws + 738304);      // 16,777,216 -> 17,515,520
  bf16*  h_buf    = (bf16*)(ws + 32803840);  // 51,200,000 + 64KB pad -> 84,069,376
  unsigned char* emb8 = (unsigned char*)(ws + 84069376); // 100,096*256 -> 109,693,952
  bf16*  fusedA   = (bf16*)(ws + 109693952); // 12,582,912 -> 122,276,864
  bf16*  hu_buf   = (bf16*)(ws + 122276864); // 8,388,608 -> 130,665,472

  // ---- packing / folding ----
  k_prep_w<<<160, 256, 0, stream>>>(Wi1, Wi1p, 130, 5, 16, 1);   // permuted (gcn-first)
  k_prep_w<<<256, 256, 0, stream>>>(Wi2, Wi2p, 256, 8, 16, 0);
  k_prep_w<<<384, 256, 0, stream>>>(Wu1, Wu1p, 384, 12, 16, 0);
  k_prep_w<<<256, 256, 0, stream>>>(Wu2, Wu2p, 256, 8, 16, 0);
  k_fold<<<17, 256, 0, stream>>>(Wq, Wk, bq, Wqkf);
  k_prep_w<<<128, 256, 0, stream>>>(Wqkf, Wqkp, 128, 4, 16, 0);
  k_prep_user<<<8192, 256, 0, stream>>>(gcn_user, fusedA);

  // ---- item tower: MR=1 pipelined persistent-B kernels (128-row tiles) ----
  const int intiles = (NITEMS + 127) / 128;  // 782 (pad rows clamped/unused)
  k_item_g1<<<256, 512, 0, stream>>>(item_feat, gcn_item, Wi1p, bi1, h_buf, intiles);
  k_gemm_pers<8, 1><<<256, 512, 0, stream>>>(h_buf, Wi2p, bi2, emb8, intiles, 256);

  // ---- user tower ----
  const int utiles = NUSERS / 32;            // 512
  const int ublk = utiles / 4;               // 128
  k_gemm<4, 16, 4, 2><<<ublk, 256, 0, stream>>>(fusedA, Wqkp, Wqkf + 128 * 256, Qt, utiles, 384);
  k_user_attn<<<NUSERS, 256, 0, stream>>>(Qt, hist_idx, hist_len, emb8, fusedA);
  k_gemm<12, 16, 0, 2><<<ublk, 256, 0, stream>>>(fusedA, Wu1p, bu1, hu_buf, utiles, 384);
  k_gemm<8, 16, 3, 2><<<ublk, 256, 0, stream>>>(hu_buf, Wu2p, bu2, (float*)d_out, utiles, 256);
}

// Round 22
// 150.148 us; speedup vs baseline: 3.1061x; 3.1061x over previous
//
#include <hip/hip_runtime.h>
#include <hip/hip_bf16.h>
#include <hip/hip_fp8.h>
#include <math.h>

#define NITEMS 100000
#define NUSERS 16384
#define HLEN   48
#define GCN    128
#define ATTN_D 128
#define HID    256
#define TOW    256

typedef __attribute__((ext_vector_type(8))) short short8;
typedef __attribute__((ext_vector_type(16))) unsigned char uchar16;
typedef __attribute__((ext_vector_type(4))) float f32x4;
typedef __hip_bfloat16 bf16;

static __device__ __forceinline__ float bfu(unsigned short u) {
  unsigned int x = ((unsigned int)u) << 16;
  float f; __builtin_memcpy(&f, &x, 4); return f;
}
static __device__ __forceinline__ short f2bf(float v) {
  bf16 h = __float2bfloat16(v);
  short s; __builtin_memcpy(&s, &h, 2); return s;
}
static __device__ __forceinline__ unsigned char f2e4m3(float v) {
  __hip_fp8_e4m3 t(v);
  return (unsigned char)t.__x;
}
static __device__ __forceinline__ float e4m3f(unsigned char b) {
  __hip_fp8_e4m3 t;
  t.__x = (__hip_fp8_storage_t)b;
  return (float)t;
}

// global->LDS direct copy, 16B per lane; lds dest = wave-uniform base + lane*16
#define GLDS16(g, l)                                                            \
  __builtin_amdgcn_global_load_lds(                                             \
      (const __attribute__((address_space(1))) unsigned int*)(g),               \
      (__attribute__((address_space(3))) unsigned int*)(l), 16, 0, 0)

// ---------------------------------------------------------------------------
// Prep: pack fp32 weight [Korig][N] -> bf16 fragment-ordered buffer.
// perm=1: source row permuted gcn-first (srck = k<128 ? k+2 : k-128).
// ---------------------------------------------------------------------------
__global__ __launch_bounds__(256) void k_prep_w(const float* __restrict__ W,
                                                bf16* __restrict__ out,
                                                int Korig, int KS, int NT, int perm) {
  int tid = blockIdx.x * 256 + threadIdx.x;
  int total = KS * NT * 512;
  if (tid >= total) return;
  int i  = tid & 7;
  int l  = (tid >> 3) & 63;
  int ct = (tid >> 9) % NT;
  int ks = (tid >> 9) / NT;
  int k   = ks * 32 + ((l >> 4) << 3) + i;
  int col = ct * 16 + (l & 15);
  int N = NT * 16;
  int srck = perm ? ((k < 128) ? (k + 2) : (k - 128)) : k;
  float v = (k < Korig) ? W[(size_t)srck * N + col] : 0.f;
  out[tid] = __float2bfloat16(v);
}

// Same fragment order but fp8 e4m3 output (for the fp8 MFMA GEMM2 B operand).
__global__ __launch_bounds__(256) void k_prep_w8(const float* __restrict__ W,
                                                 unsigned char* __restrict__ out,
                                                 int KS, int NT) {
  int tid = blockIdx.x * 256 + threadIdx.x;
  int total = KS * NT * 512;
  if (tid >= total) return;
  int i  = tid & 7;
  int l  = (tid >> 3) & 63;
  int ct = (tid >> 9) % NT;
  int ks = (tid >> 9) / NT;
  int k   = ks * 32 + ((l >> 4) << 3) + i;
  int col = ct * 16 + (l & 15);
  out[tid] = f2e4m3(W[(size_t)k * (NT * 16) + col]);
}

__global__ __launch_bounds__(256) void k_prep_user(const float* __restrict__ gcn_user,
                                                   bf16* __restrict__ fused) {
  int tid = blockIdx.x * 256 + threadIdx.x;
  if (tid >= NUSERS * GCN) return;
  int k = tid & 127;
  int u = tid >> 7;
  fused[(size_t)u * (GCN + TOW) + k] = __float2bfloat16(gcn_user[tid]);
}

// ---------------------------------------------------------------------------
// Fold: Wqk[g][t] = (1/sqrt(128)) * sum_d Wq[g][d] * Wk[t][d]   (g<128)
//       b~[t]    = (1/sqrt(128)) * sum_d bq[d]    * Wk[t][d]    (block 16)
// ---------------------------------------------------------------------------
__global__ __launch_bounds__(256) void k_fold(const float* __restrict__ Wq,
                                              const float* __restrict__ Wk,
                                              const float* __restrict__ bq,
                                              float* __restrict__ out) {
  const float INV_S = 0.08838834764831845f;
  const int t = threadIdx.x;
  const int b = blockIdx.x;
  if (b < 16) {
    __shared__ float wq[8][128];
    for (int s = t; s < 8 * 128; s += 256)
      wq[s >> 7][s & 127] = Wq[(size_t)(b * 8 + (s >> 7)) * ATTN_D + (s & 127)];
    __syncthreads();
    float acc[8] = {0.f, 0.f, 0.f, 0.f, 0.f, 0.f, 0.f, 0.f};
    for (int d = 0; d < 128; ++d) {
      const float wk = Wk[(size_t)t * ATTN_D + d];
      #pragma unroll
      for (int gg = 0; gg < 8; ++gg) acc[gg] = fmaf(wq[gg][d], wk, acc[gg]);
    }
    #pragma unroll
    for (int gg = 0; gg < 8; ++gg)
      out[(size_t)(b * 8 + gg) * TOW + t] = acc[gg] * INV_S;
  } else {
    float a = 0.f;
    for (int d = 0; d < 128; ++d)
      a = fmaf(bq[d], Wk[(size_t)t * ATTN_D + d], a);
    out[(size_t)128 * TOW + t] = a * INV_S;
  }
}

// ---------------------------------------------------------------------------
// Item GEMM1, fused input cast (round-20 structure): h8 = fp8(relu(A@W1p+b1)).
// MR=2, 256-row tiles, 80KB persistent W1p, barrier-free grind.
// ---------------------------------------------------------------------------
__global__ __launch_bounds__(512, 2) void k_item_g1(
    const float* __restrict__ feat,
    const float* __restrict__ gcn,
    const bf16* __restrict__ Wf,      // packed KS=5, NT=16, perm gcn-first
    const float* __restrict__ bias,
    unsigned char* __restrict__ h_out, // fp8 e4m3
    int ntiles)
{
  __shared__ bf16 bs[5 * 8192];       // 80 KB = full W1p
  const int j = threadIdx.x;
  const int l = j & 63;
  const int w = j >> 6;               // 0..7 row-wave
  const int r = l & 15, g = l >> 4;
  const int jb = (j & ~63) * 8;

  #pragma unroll
  for (int s = 0; s < 10; ++s)
    GLDS16(Wf + (size_t)s * 4096 + (size_t)j * 8, &bs[s * 4096 + jb]);

  float bj[16];
  #pragma unroll
  for (int ct = 0; ct < 16; ++ct) bj[ct] = bias[ct * 16 + r];

  __syncthreads();   // only barrier

  for (int t = blockIdx.x; t < ntiles; t += gridDim.x) {
    const int R0 = t * 256 + w * 32;
    int row0 = R0 + r;      if (row0 >= NITEMS) row0 = NITEMS - 1;
    int row1 = R0 + 16 + r; if (row1 >= NITEMS) row1 = NITEMS - 1;
    const float* g0 = gcn + (size_t)row0 * GCN;
    const float* g1 = gcn + (size_t)row1 * GCN;

    f32x4 acc[2][16];
    #pragma unroll
    for (int mr = 0; mr < 2; ++mr)
      #pragma unroll
      for (int ct = 0; ct < 16; ++ct) acc[mr][ct] = (f32x4){0.f, 0.f, 0.f, 0.f};

    #pragma unroll
    for (int ks = 0; ks < 5; ++ks) {
      short8 a0, a1;
      if (ks < 4) {
        const float4* p0 = (const float4*)(g0 + ks * 32 + g * 8);
        const float4* p1 = (const float4*)(g1 + ks * 32 + g * 8);
        float4 x0 = p0[0], y0 = p0[1];
        float4 x1 = p1[0], y1 = p1[1];
        a0[0] = f2bf(x0.x); a0[1] = f2bf(x0.y); a0[2] = f2bf(x0.z); a0[3] = f2bf(x0.w);
        a0[4] = f2bf(y0.x); a0[5] = f2bf(y0.y); a0[6] = f2bf(y0.z); a0[7] = f2bf(y0.w);
        a1[0] = f2bf(x1.x); a1[1] = f2bf(x1.y); a1[2] = f2bf(x1.z); a1[3] = f2bf(x1.w);
        a1[4] = f2bf(y1.x); a1[5] = f2bf(y1.y); a1[6] = f2bf(y1.z); a1[7] = f2bf(y1.w);
      } else {
        a0 = (short8){0, 0, 0, 0, 0, 0, 0, 0};
        a1 = (short8){0, 0, 0, 0, 0, 0, 0, 0};
        if (g == 0) {
          a0[0] = f2bf(feat[(size_t)row0 * 2]);
          a0[1] = f2bf(feat[(size_t)row0 * 2 + 1]);
          a1[0] = f2bf(feat[(size_t)row1 * 2]);
          a1[1] = f2bf(feat[(size_t)row1 * 2 + 1]);
        }
      }
      const bf16* wb = bs + (size_t)(ks * 16) * 512 + (size_t)l * 8;
      #pragma unroll
      for (int ct = 0; ct < 16; ++ct) {
        short8 b = *(const short8*)(wb + ct * 512);
        acc[0][ct] = __builtin_amdgcn_mfma_f32_16x16x32_bf16(a0, b, acc[0][ct], 0, 0, 0);
        acc[1][ct] = __builtin_amdgcn_mfma_f32_16x16x32_bf16(a1, b, acc[1][ct], 0, 0, 0);
      }
    }

    #pragma unroll
    for (int mr = 0; mr < 2; ++mr)
      #pragma unroll
      for (int ct = 0; ct < 16; ++ct)
        #pragma unroll
        for (int i = 0; i < 4; ++i)
          h_out[(size_t)(R0 + mr * 16 + g * 4 + i) * 256 + ct * 16 + r] =
              f2e4m3(fmaxf(acc[mr][ct][i] + bj[ct], 0.f));
  }
}

// ---------------------------------------------------------------------------
// GEMM2 in fp8: emb8 = fp8(l2norm(h8 @ W2f8 + b2)).
// Persistent fp8 B = 64KB LDS -> 2 blocks/CU; launch_bounds(512,4) -> 128
// unified regs/wave (acc = 64 AGPR, MR=1). mfma_f32_16x16x32_fp8_fp8, K=32
// steps, 8-byte fragments. 128-row tiles, barrier-free grind.
// ---------------------------------------------------------------------------
__global__ __launch_bounds__(512, 4) void k_gemm2_f8(
    const unsigned char* __restrict__ A8,   // [rows][256] fp8 (h)
    const unsigned char* __restrict__ Wf8,  // packed KS=8, NT=16, fp8
    const float* __restrict__ bias,
    unsigned char* __restrict__ Cout,       // [rows][256] fp8 (emb)
    int ntiles)
{
  __shared__ unsigned char bs8[8 * 8192];   // 64 KB = full fp8 B
  const int j = threadIdx.x;
  const int l = j & 63;
  const int w = j >> 6;               // 0..7 row-wave
  const int r = l & 15, g = l >> 4;
  const int jb = (j & ~63) * 16;      // wave-uniform LDS byte base

  // stage full fp8 B once: 8 sweeps x 8KB (512 lanes x 16B)
  #pragma unroll
  for (int s = 0; s < 8; ++s)
    GLDS16(Wf8 + (size_t)s * 8192 + (size_t)j * 16, &bs8[s * 8192 + jb]);

  __syncthreads();   // only barrier

  for (int t = blockIdx.x; t < ntiles; t += gridDim.x) {
    const int R0 = t * 128 + w * 16;
    const unsigned char* arow = A8 + (size_t)(R0 + r) * 256 + g * 8;
    const unsigned char* wbase = bs8 + (size_t)l * 8;

    f32x4 acc[16];
    #pragma unroll
    for (int ct = 0; ct < 16; ++ct) acc[ct] = (f32x4){0.f, 0.f, 0.f, 0.f};

    #pragma unroll 1
    for (int ks = 0; ks < 8; ++ks) {
      long a;
      __builtin_memcpy(&a, arow + ks * 32, 8);
      const unsigned char* wb = wbase + (size_t)(ks * 16) * 512;
      #pragma unroll
      for (int ct = 0; ct < 16; ++ct) {
        long b;
        __builtin_memcpy(&b, wb + ct * 512, 8);
        acc[ct] = __builtin_amdgcn_mfma_f32_16x16x32_fp8_fp8(a, b, acc[ct], 0, 0, 0);
      }
    }

    // bias + l2norm + fp8 store (row = R0+g*4+i, col = ct*16+r)
    float s[4] = {0.f, 0.f, 0.f, 0.f};
    #pragma unroll
    for (int ct = 0; ct < 16; ++ct) {
      const float bj = bias[ct * 16 + r];
      #pragma unroll
      for (int i = 0; i < 4; ++i) {
        acc[ct][i] += bj;
        s[i] += acc[ct][i] * acc[ct][i];
      }
    }
    #pragma unroll
    for (int off = 1; off < 16; off <<= 1) {
      #pragma unroll
      for (int i = 0; i < 4; ++i) s[i] += __shfl_xor(s[i], off);
    }
    float rn[4];
    #pragma unroll
    for (int i = 0; i < 4; ++i) rn[i] = 1.f / fmaxf(sqrtf(s[i]), 1e-12f);
    #pragma unroll
    for (int ct = 0; ct < 16; ++ct)
      #pragma unroll
      for (int i = 0; i < 4; ++i)
        Cout[(size_t)(R0 + g * 4 + i) * 256 + ct * 16 + r] =
            f2e4m3(acc[ct][i] * rn[i]);
  }
}

// ---------------------------------------------------------------------------
// Generic MFMA GEMM (user tower), LDS-staged double-buffered B, 4 waves.
// MODE 0: relu->bf16; 3: l2norm->fp32; 4: plain->fp32
// ---------------------------------------------------------------------------
template<int KS, int NT, int MODE, int MR>
__global__ __launch_bounds__(256) void k_gemm(
    const bf16* __restrict__ A,
    const bf16* __restrict__ Wf,
    const float* __restrict__ bias,
    void* __restrict__ Cout,
    int Mtiles, int Astride)
{
  static_assert(NT % 4 == 0, "NT must be divisible by 4");
  constexpr int BSZ = NT * 512;
  constexpr int CH  = NT / 4;
  __shared__ bf16 bs[2][BSZ];
  const int j   = threadIdx.x;
  const int l   = j & 63;
  const int wid = j >> 6;
  int tile = blockIdx.x * 4 + wid;
  if (tile >= Mtiles) tile = Mtiles - 1;
  const int N = NT * 16;
  const int r = l & 15, g = l >> 4;

  {
    const short8* src = (const short8*)Wf;
    short8* dst = (short8*)bs[0];
    #pragma unroll
    for (int c = 0; c < CH; ++c) dst[c * 256 + j] = src[c * 256 + j];
  }

  f32x4 acc[MR][NT];
  #pragma unroll
  for (int mr = 0; mr < MR; ++mr)
    #pragma unroll
    for (int ct = 0; ct < NT; ++ct) acc[mr][ct] = (f32x4){0.f, 0.f, 0.f, 0.f};

  const bf16* arow[MR];
  #pragma unroll
  for (int mr = 0; mr < MR; ++mr)
    arow[mr] = A + (size_t)(tile * (16 * MR) + mr * 16 + r) * Astride + g * 8;

  __syncthreads();

  #pragma unroll
  for (int ks = 0; ks < KS; ++ks) {
    const int cur = ks & 1;
    short8 a[MR];
    #pragma unroll
    for (int mr = 0; mr < MR; ++mr) a[mr] = *(const short8*)(arow[mr] + ks * 32);
    short8 st[CH];
    if (ks + 1 < KS) {
      const short8* src = (const short8*)(Wf + (size_t)(ks + 1) * BSZ);
      #pragma unroll
      for (int c = 0; c < CH; ++c) st[c] = src[c * 256 + j];
    }
    const bf16* wb = bs[cur] + (size_t)l * 8;
    #pragma unroll
    for (int ct = 0; ct < NT; ++ct) {
      short8 b = *(const short8*)(wb + ct * 512);
      #pragma unroll
      for (int mr = 0; mr < MR; ++mr)
        acc[mr][ct] = __builtin_amdgcn_mfma_f32_16x16x32_bf16(a[mr], b, acc[mr][ct], 0, 0, 0);
    }
    if (ks + 1 < KS) {
      short8* dst = (short8*)bs[cur ^ 1];
      #pragma unroll
      for (int c = 0; c < CH; ++c) dst[c * 256 + j] = st[c];
    }
    __syncthreads();
  }

  #pragma unroll
  for (int mr = 0; mr < MR; ++mr) {
    #pragma unroll
    for (int ct = 0; ct < NT; ++ct) {
      const float bj = bias[ct * 16 + r];
      #pragma unroll
      for (int i = 0; i < 4; ++i) acc[mr][ct][i] += bj;
    }
  }

  if (MODE == 0 || MODE == 2 || MODE == 4) {
    #pragma unroll
    for (int mr = 0; mr < MR; ++mr)
      #pragma unroll
      for (int ct = 0; ct < NT; ++ct)
        #pragma unroll
        for (int i = 0; i < 4; ++i) {
          float v = acc[mr][ct][i];
          if (MODE == 0) v = fmaxf(v, 0.f);
          size_t off = (size_t)(tile * (16 * MR) + mr * 16 + g * 4 + i) * N + ct * 16 + r;
          if (MODE == 4) ((float*)Cout)[off] = v;
          else           ((bf16*)Cout)[off]  = __float2bfloat16(v);
        }
  } else {
    #pragma unroll
    for (int mr = 0; mr < MR; ++mr) {
      float s[4] = {0.f, 0.f, 0.f, 0.f};
      #pragma unroll
      for (int ct = 0; ct < NT; ++ct)
        #pragma unroll
        for (int i = 0; i < 4; ++i) s[i] += acc[mr][ct][i] * acc[mr][ct][i];
      #pragma unroll
      for (int off = 1; off < 16; off <<= 1) {
        #pragma unroll
        for (int i = 0; i < 4; ++i) s[i] += __shfl_xor(s[i], off);
      }
      float rn[4];
      #pragma unroll
      for (int i = 0; i < 4; ++i) rn[i] = 1.f / fmaxf(sqrtf(s[i]), 1e-12f);
      #pragma unroll
      for (int ct = 0; ct < NT; ++ct)
        #pragma unroll
        for (int i = 0; i < 4; ++i) {
          size_t off = (size_t)(tile * (16 * MR) + mr * 16 + g * 4 + i) * N + ct * 16 + r;
          float v = acc[mr][ct][i] * rn[i];
          if (MODE == 3) ((float*)Cout)[off] = v;
          else           ((bf16*)Cout)[off]  = __float2bfloat16(v);
        }
    }
  }
}

// ---------------------------------------------------------------------------
// Attention v7-fp8: 16-lane row groups, no-max softmax (|s|<0.1 by
// construction), fp8 e4m3 embeddings (one 16B load/lane/row).
// ---------------------------------------------------------------------------
__global__ __launch_bounds__(256) void k_user_attn(
    const float* __restrict__ Qt,          // [NUSERS][TOW] fp32 (Wqk-folded)
    const int*   __restrict__ hist_idx,
    const int*   __restrict__ hist_len,
    const unsigned char* __restrict__ emb8,// [rows][TOW] fp8 e4m3 (normalized)
    bf16* __restrict__ fused)
{
  const int u = blockIdx.x;
  const int j = threadIdx.x;
  const int wid = j >> 6, lane = j & 63;
  const int g = lane >> 4, r = lane & 15;
  const int part = wid * 4 + g;
  __shared__ int   idx[HLEN];
  __shared__ float redO[16][TOW + 4];
  __shared__ float redL[16];

  const int nv = hist_len[u] + 1;

  if (j < HLEN) idx[j] = hist_idx[u * HLEN + j];
  const float* qp = Qt + (size_t)u * TOW + r * 16;
  f32x4 q0 = *(const f32x4*)(qp);
  f32x4 q1 = *(const f32x4*)(qp + 4);
  f32x4 q2 = *(const f32x4*)(qp + 8);
  f32x4 q3 = *(const f32x4*)(qp + 12);
  __syncthreads();

  float l = 0.f;
  f32x4 O0 = (f32x4){0.f,0.f,0.f,0.f}, O1 = O0, O2 = O0, O3 = O0;

  for (int h = part; h < nv; h += 16) {
    const uchar16 e = *(const uchar16*)(emb8 + (size_t)idx[h] * TOW + r * 16);
    float ef[16];
    #pragma unroll
    for (int i = 0; i < 16; ++i) ef[i] = e4m3f(e[i]);

    float sc = q0.x*ef[0] + q0.y*ef[1] + q0.z*ef[2] + q0.w*ef[3]
             + q1.x*ef[4] + q1.y*ef[5] + q1.z*ef[6] + q1.w*ef[7]
             + q2.x*ef[8] + q2.y*ef[9] + q2.z*ef[10]+ q2.w*ef[11]
             + q3.x*ef[12]+ q3.y*ef[13]+ q3.z*ef[14]+ q3.w*ef[15];
    #pragma unroll
    for (int off = 1; off < 16; off <<= 1) sc += __shfl_xor(sc, off);
    const float p = __expf(sc);
    l += p;
    O0.x += p*ef[0];  O0.y += p*ef[1];  O0.z += p*ef[2];  O0.w += p*ef[3];
    O1.x += p*ef[4];  O1.y += p*ef[5];  O1.z += p*ef[6];  O1.w += p*ef[7];
    O2.x += p*ef[8];  O2.y += p*ef[9];  O2.z += p*ef[10]; O2.w += p*ef[11];
    O3.x += p*ef[12]; O3.y += p*ef[13]; O3.z += p*ef[14]; O3.w += p*ef[15];
  }

  *(f32x4*)(&redO[part][r * 16])      = O0;
  *(f32x4*)(&redO[part][r * 16 + 4])  = O1;
  *(f32x4*)(&redO[part][r * 16 + 8])  = O2;
  *(f32x4*)(&redO[part][r * 16 + 12]) = O3;
  if (r == 0) redL[part] = l;
  __syncthreads();

  float L = 0.f, val = 0.f;
  #pragma unroll
  for (int w = 0; w < 16; ++w) {
    L   += redL[w];
    val += redO[w][j];
  }
  fused[(size_t)u * (GCN + TOW) + GCN + j] = __float2bfloat16(val / L);
}

// ---------------------------------------------------------------------------
extern "C" void kernel_launch(void* const* d_in, const int* in_sizes, int n_in,
                              void* d_out, int out_size, void* d_ws, size_t ws_size,
                              hipStream_t stream) {
  const float* item_feat = (const float*)d_in[0];
  const float* gcn_item  = (const float*)d_in[1];
  const float* gcn_user  = (const float*)d_in[2];
  const int*   hist_idx  = (const int*)d_in[3];
  const int*   hist_len  = (const int*)d_in[4];
  const float* Wi1 = (const float*)d_in[5];
  const float* bi1 = (const float*)d_in[6];
  const float* Wi2 = (const float*)d_in[7];
  const float* bi2 = (const float*)d_in[8];
  const float* Wq  = (const float*)d_in[9];
  const float* bq  = (const float*)d_in[10];
  const float* Wk  = (const float*)d_in[11];
  const float* bk  = (const float*)d_in[12];  // cancels in softmax
  const float* Wu1 = (const float*)d_in[13];
  const float* bu1 = (const float*)d_in[14];
  const float* Wu2 = (const float*)d_in[15];
  const float* bu2 = (const float*)d_in[16];
  (void)bk;

  char* ws = (char*)d_ws;
  bf16*  Wi1p  = (bf16*)(ws + 0);            // 81,920 B
  unsigned char* Wi2p8 = (unsigned char*)(ws + 81920);  // 65,536 -> 147,456
  bf16*  Wu1p  = (bf16*)(ws + 147456);       // 196,608 -> 344,064
  bf16*  Wu2p  = (bf16*)(ws + 344064);       // 131,072 -> 475,136
  float* Wqkf  = (float*)(ws + 475136);      // 132,096 -> 607,232
  bf16*  Wqkp  = (bf16*)(ws + 607232);       // 65,536 -> 672,768
  float* Qt    = (float*)(ws + 672768);      // 16,777,216 -> 17,449,984
  unsigned char* h8   = (unsigned char*)(ws + 17449984); // 100,096*256 -> 43,074,560
  unsigned char* emb8 = (unsigned char*)(ws + 43074560); // 100,096*256 -> 68,699,136
  bf16*  fusedA   = (bf16*)(ws + 68699136);  // 12,582,912 -> 81,282,048
  bf16*  hu_buf   = (bf16*)(ws + 81282048);  // 8,388,608 -> 89,670,656

  // ---- packing / folding ----
  k_prep_w<<<160, 256, 0, stream>>>(Wi1, Wi1p, 130, 5, 16, 1);   // permuted (gcn-first)
  k_prep_w8<<<256, 256, 0, stream>>>(Wi2, Wi2p8, 8, 16);
  k_prep_w<<<384, 256, 0, stream>>>(Wu1, Wu1p, 384, 12, 16, 0);
  k_prep_w<<<256, 256, 0, stream>>>(Wu2, Wu2p, 256, 8, 16, 0);
  k_fold<<<17, 256, 0, stream>>>(Wq, Wk, bq, Wqkf);
  k_prep_w<<<128, 256, 0, stream>>>(Wqkf, Wqkp, 128, 4, 16, 0);
  k_prep_user<<<8192, 256, 0, stream>>>(gcn_user, fusedA);

  // ---- item tower ----
  const int i256 = (NITEMS + 255) / 256;     // 391 (256-row tiles, g1)
  const int i128 = (NITEMS + 127) / 128;     // 782 (128-row tiles, gemm2)
  k_item_g1<<<256, 512, 0, stream>>>(item_feat, gcn_item, Wi1p, bi1, h8, i256);
  k_gemm2_f8<<<512, 512, 0, stream>>>(h8, Wi2p8, bi2, emb8, i128);

  // ---- user tower ----
  const int utiles = NUSERS / 32;            // 512
  const int ublk = utiles / 4;               // 128
  k_gemm<4, 16, 4, 2><<<ublk, 256, 0, stream>>>(fusedA, Wqkp, Wqkf + 128 * 256, Qt, utiles, 384);
  k_user_attn<<<NUSERS, 256, 0, stream>>>(Qt, hist_idx, hist_len, emb8, fusedA);
  k_gemm<12, 16, 0, 2><<<ublk, 256, 0, stream>>>(fusedA, Wu1p, bu1, hu_buf, utiles, 384);
  k_gemm<8, 16, 3, 2><<<ublk, 256, 0, stream>>>(hu_buf, Wu2p, bu2, (float*)d_out, utiles, 256);
}

// Round 23
// 148.670 us; speedup vs baseline: 3.1370x; 1.0099x over previous
//
#include <hip/hip_runtime.h>
#include <hip/hip_bf16.h>
#include <hip/hip_fp8.h>
#include <math.h>

#define NITEMS 100000
#define NUSERS 16384
#define HLEN   48
#define GCN    128
#define ATTN_D 128
#define HID    256
#define TOW    256

typedef __attribute__((ext_vector_type(8))) short short8;
typedef __attribute__((ext_vector_type(16))) unsigned char uchar16;
typedef __attribute__((ext_vector_type(4))) float f32x4;
typedef __hip_bfloat16 bf16;

static __device__ __forceinline__ float bfu(unsigned short u) {
  unsigned int x = ((unsigned int)u) << 16;
  float f; __builtin_memcpy(&f, &x, 4); return f;
}
static __device__ __forceinline__ short f2bf(float v) {
  bf16 h = __float2bfloat16(v);
  short s; __builtin_memcpy(&s, &h, 2); return s;
}
static __device__ __forceinline__ unsigned char f2e4m3(float v) {
  __hip_fp8_e4m3 t(v);
  return (unsigned char)t.__x;
}
static __device__ __forceinline__ float e4m3f(unsigned char b) {
  __hip_fp8_e4m3 t;
  t.__x = (__hip_fp8_storage_t)b;
  return (float)t;
}

// global->LDS direct copy, 16B per lane; lds dest = wave-uniform base + lane*16
#define GLDS16(g, l)                                                            \
  __builtin_amdgcn_global_load_lds(                                             \
      (const __attribute__((address_space(1))) unsigned int*)(g),               \
      (__attribute__((address_space(3))) unsigned int*)(l), 16, 0, 0)

// ---------------------------------------------------------------------------
// Prep: pack fp32 weight [Korig][N] -> bf16 fragment-ordered buffer.
// perm=1: source row permuted gcn-first (srck = k<128 ? k+2 : k-128).
// ---------------------------------------------------------------------------
__global__ __launch_bounds__(256) void k_prep_w(const float* __restrict__ W,
                                                bf16* __restrict__ out,
                                                int Korig, int KS, int NT, int perm) {
  int tid = blockIdx.x * 256 + threadIdx.x;
  int total = KS * NT * 512;
  if (tid >= total) return;
  int i  = tid & 7;
  int l  = (tid >> 3) & 63;
  int ct = (tid >> 9) % NT;
  int ks = (tid >> 9) / NT;
  int k   = ks * 32 + ((l >> 4) << 3) + i;
  int col = ct * 16 + (l & 15);
  int N = NT * 16;
  int srck = perm ? ((k < 128) ? (k + 2) : (k - 128)) : k;
  float v = (k < Korig) ? W[(size_t)srck * N + col] : 0.f;
  out[tid] = __float2bfloat16(v);
}

// Same fragment order but fp8 e4m3 output (for the fp8 MFMA GEMM2 B operand).
__global__ __launch_bounds__(256) void k_prep_w8(const float* __restrict__ W,
                                                 unsigned char* __restrict__ out,
                                                 int KS, int NT) {
  int tid = blockIdx.x * 256 + threadIdx.x;
  int total = KS * NT * 512;
  if (tid >= total) return;
  int i  = tid & 7;
  int l  = (tid >> 3) & 63;
  int ct = (tid >> 9) % NT;
  int ks = (tid >> 9) / NT;
  int k   = ks * 32 + ((l >> 4) << 3) + i;
  int col = ct * 16 + (l & 15);
  out[tid] = f2e4m3(W[(size_t)k * (NT * 16) + col]);
}

__global__ __launch_bounds__(256) void k_prep_user(const float* __restrict__ gcn_user,
                                                   bf16* __restrict__ fused) {
  int tid = blockIdx.x * 256 + threadIdx.x;
  if (tid >= NUSERS * GCN) return;
  int k = tid & 127;
  int u = tid >> 7;
  fused[(size_t)u * (GCN + TOW) + k] = __float2bfloat16(gcn_user[tid]);
}

// ---------------------------------------------------------------------------
// Fold: Wqk[g][t] = (1/sqrt(128)) * sum_d Wq[g][d] * Wk[t][d]   (g<128)
//       b~[t]    = (1/sqrt(128)) * sum_d bq[d]    * Wk[t][d]    (block 16)
// ---------------------------------------------------------------------------
__global__ __launch_bounds__(256) void k_fold(const float* __restrict__ Wq,
                                              const float* __restrict__ Wk,
                                              const float* __restrict__ bq,
                                              float* __restrict__ out) {
  const float INV_S = 0.08838834764831845f;
  const int t = threadIdx.x;
  const int b = blockIdx.x;
  if (b < 16) {
    __shared__ float wq[8][128];
    for (int s = t; s < 8 * 128; s += 256)
      wq[s >> 7][s & 127] = Wq[(size_t)(b * 8 + (s >> 7)) * ATTN_D + (s & 127)];
    __syncthreads();
    float acc[8] = {0.f, 0.f, 0.f, 0.f, 0.f, 0.f, 0.f, 0.f};
    for (int d = 0; d < 128; ++d) {
      const float wk = Wk[(size_t)t * ATTN_D + d];
      #pragma unroll
      for (int gg = 0; gg < 8; ++gg) acc[gg] = fmaf(wq[gg][d], wk, acc[gg]);
    }
    #pragma unroll
    for (int gg = 0; gg < 8; ++gg)
      out[(size_t)(b * 8 + gg) * TOW + t] = acc[gg] * INV_S;
  } else {
    float a = 0.f;
    for (int d = 0; d < 128; ++d)
      a = fmaf(bq[d], Wk[(size_t)t * ATTN_D + d], a);
    out[(size_t)128 * TOW + t] = a * INV_S;
  }
}

// ---------------------------------------------------------------------------
// Item GEMM1 v2: h8 = fp8(relu(gcn@W1gcn + feat-rank2 + b1)).
// MFMA loop covers only the gcn K=128 (ks=0..3, 64KB persistent LDS B);
// the 2-dim feat contribution is applied in the epilogue as fp32 FMAs with
// Wi1 rows 0,1 staged in LDS (more accurate than the bf16 MFMA path).
// MR=1, 128-row tiles, launch_bounds(512,4) -> 4 waves/SIMD, 2 blocks/CU.
// ---------------------------------------------------------------------------
__global__ __launch_bounds__(512, 4) void k_item_g1(
    const float* __restrict__ feat,
    const float* __restrict__ gcn,
    const bf16* __restrict__ Wf,      // packed KS=5 (ks=0..3 used), perm gcn-first
    const float* __restrict__ Wi1raw, // original fp32 Wi1 [130][256]
    const float* __restrict__ bias,
    unsigned char* __restrict__ h_out, // fp8 e4m3
    int ntiles)
{
  __shared__ bf16  bs[4 * 8192];      // 64 KB = gcn part of W1p
  __shared__ float wfeat[512];        // Wi1 rows 0,1 (fp32)
  const int j = threadIdx.x;
  const int l = j & 63;
  const int w = j >> 6;               // 0..7 row-wave
  const int r = l & 15, g = l >> 4;
  const int jb = (j & ~63) * 8;

  #pragma unroll
  for (int s = 0; s < 8; ++s)
    GLDS16(Wf + (size_t)s * 4096 + (size_t)j * 8, &bs[s * 4096 + jb]);
  wfeat[j] = Wi1raw[j];

  float bj[16];
  #pragma unroll
  for (int ct = 0; ct < 16; ++ct) bj[ct] = bias[ct * 16 + r];

  __syncthreads();   // only barrier

  for (int t = blockIdx.x; t < ntiles; t += gridDim.x) {
    const int R0 = t * 128 + w * 16;
    int arow = R0 + r; if (arow >= NITEMS) arow = NITEMS - 1;
    const float* grow = gcn + (size_t)arow * GCN;

    f32x4 acc[16];
    #pragma unroll
    for (int ct = 0; ct < 16; ++ct) acc[ct] = (f32x4){0.f, 0.f, 0.f, 0.f};

    #pragma unroll 1
    for (int ks = 0; ks < 4; ++ks) {
      const float4* p = (const float4*)(grow + ks * 32 + g * 8);
      float4 x = p[0], y = p[1];
      short8 a;
      a[0] = f2bf(x.x); a[1] = f2bf(x.y); a[2] = f2bf(x.z); a[3] = f2bf(x.w);
      a[4] = f2bf(y.x); a[5] = f2bf(y.y); a[6] = f2bf(y.z); a[7] = f2bf(y.w);
      const bf16* wb = bs + (size_t)(ks * 16) * 512 + (size_t)l * 8;
      #pragma unroll
      for (int ct = 0; ct < 16; ++ct) {
        short8 b = *(const short8*)(wb + ct * 512);
        acc[ct] = __builtin_amdgcn_mfma_f32_16x16x32_bf16(a, b, acc[ct], 0, 0, 0);
      }
    }

    // epilogue: feat rank-2 + bias + relu -> fp8 (lane rows R0+g*4+i)
    float f0[4], f1[4];
    #pragma unroll
    for (int i = 0; i < 4; ++i) {
      int orow = R0 + g * 4 + i; if (orow >= NITEMS) orow = NITEMS - 1;
      float2 fv = *(const float2*)(feat + (size_t)orow * 2);
      f0[i] = fv.x; f1[i] = fv.y;
    }
    #pragma unroll
    for (int ct = 0; ct < 16; ++ct) {
      const float w0 = wfeat[ct * 16 + r];
      const float w1 = wfeat[256 + ct * 16 + r];
      #pragma unroll
      for (int i = 0; i < 4; ++i) {
        float v = acc[ct][i] + bj[ct];
        v = fmaf(f0[i], w0, v);
        v = fmaf(f1[i], w1, v);
        h_out[(size_t)(R0 + g * 4 + i) * 256 + ct * 16 + r] =
            f2e4m3(fmaxf(v, 0.f));
      }
    }
  }
}

// ---------------------------------------------------------------------------
// GEMM2 in fp8: emb8 = fp8(l2norm(h8 @ W2f8 + b2)).
// Persistent fp8 B = 64KB LDS -> 2 blocks/CU; launch_bounds(512,4).
// ---------------------------------------------------------------------------
__global__ __launch_bounds__(512, 4) void k_gemm2_f8(
    const unsigned char* __restrict__ A8,   // [rows][256] fp8 (h)
    const unsigned char* __restrict__ Wf8,  // packed KS=8, NT=16, fp8
    const float* __restrict__ bias,
    unsigned char* __restrict__ Cout,       // [rows][256] fp8 (emb)
    int ntiles)
{
  __shared__ unsigned char bs8[8 * 8192];   // 64 KB = full fp8 B
  const int j = threadIdx.x;
  const int l = j & 63;
  const int w = j >> 6;               // 0..7 row-wave
  const int r = l & 15, g = l >> 4;
  const int jb = (j & ~63) * 16;      // wave-uniform LDS byte base

  #pragma unroll
  for (int s = 0; s < 8; ++s)
    GLDS16(Wf8 + (size_t)s * 8192 + (size_t)j * 16, &bs8[s * 8192 + jb]);

  __syncthreads();   // only barrier

  for (int t = blockIdx.x; t < ntiles; t += gridDim.x) {
    const int R0 = t * 128 + w * 16;
    const unsigned char* arow = A8 + (size_t)(R0 + r) * 256 + g * 8;
    const unsigned char* wbase = bs8 + (size_t)l * 8;

    f32x4 acc[16];
    #pragma unroll
    for (int ct = 0; ct < 16; ++ct) acc[ct] = (f32x4){0.f, 0.f, 0.f, 0.f};

    #pragma unroll 1
    for (int ks = 0; ks < 8; ++ks) {
      long a;
      __builtin_memcpy(&a, arow + ks * 32, 8);
      const unsigned char* wb = wbase + (size_t)(ks * 16) * 512;
      #pragma unroll
      for (int ct = 0; ct < 16; ++ct) {
        long b;
        __builtin_memcpy(&b, wb + ct * 512, 8);
        acc[ct] = __builtin_amdgcn_mfma_f32_16x16x32_fp8_fp8(a, b, acc[ct], 0, 0, 0);
      }
    }

    float s[4] = {0.f, 0.f, 0.f, 0.f};
    #pragma unroll
    for (int ct = 0; ct < 16; ++ct) {
      const float bj = bias[ct * 16 + r];
      #pragma unroll
      for (int i = 0; i < 4; ++i) {
        acc[ct][i] += bj;
        s[i] += acc[ct][i] * acc[ct][i];
      }
    }
    #pragma unroll
    for (int off = 1; off < 16; off <<= 1) {
      #pragma unroll
      for (int i = 0; i < 4; ++i) s[i] += __shfl_xor(s[i], off);
    }
    float rn[4];
    #pragma unroll
    for (int i = 0; i < 4; ++i) rn[i] = 1.f / fmaxf(sqrtf(s[i]), 1e-12f);
    #pragma unroll
    for (int ct = 0; ct < 16; ++ct)
      #pragma unroll
      for (int i = 0; i < 4; ++i)
        Cout[(size_t)(R0 + g * 4 + i) * 256 + ct * 16 + r] =
            f2e4m3(acc[ct][i] * rn[i]);
  }
}

// ---------------------------------------------------------------------------
// Generic MFMA GEMM (user tower), LDS-staged double-buffered B, 4 waves.
// MODE 0: relu->bf16; 3: l2norm->fp32; 4: plain->fp32
// ---------------------------------------------------------------------------
template<int KS, int NT, int MODE, int MR>
__global__ __launch_bounds__(256) void k_gemm(
    const bf16* __restrict__ A,
    const bf16* __restrict__ Wf,
    const float* __restrict__ bias,
    void* __restrict__ Cout,
    int Mtiles, int Astride)
{
  static_assert(NT % 4 == 0, "NT must be divisible by 4");
  constexpr int BSZ = NT * 512;
  constexpr int CH  = NT / 4;
  __shared__ bf16 bs[2][BSZ];
  const int j   = threadIdx.x;
  const int l   = j & 63;
  const int wid = j >> 6;
  int tile = blockIdx.x * 4 + wid;
  if (tile >= Mtiles) tile = Mtiles - 1;
  const int N = NT * 16;
  const int r = l & 15, g = l >> 4;

  {
    const short8* src = (const short8*)Wf;
    short8* dst = (short8*)bs[0];
    #pragma unroll
    for (int c = 0; c < CH; ++c) dst[c * 256 + j] = src[c * 256 + j];
  }

  f32x4 acc[MR][NT];
  #pragma unroll
  for (int mr = 0; mr < MR; ++mr)
    #pragma unroll
    for (int ct = 0; ct < NT; ++ct) acc[mr][ct] = (f32x4){0.f, 0.f, 0.f, 0.f};

  const bf16* arow[MR];
  #pragma unroll
  for (int mr = 0; mr < MR; ++mr)
    arow[mr] = A + (size_t)(tile * (16 * MR) + mr * 16 + r) * Astride + g * 8;

  __syncthreads();

  #pragma unroll
  for (int ks = 0; ks < KS; ++ks) {
    const int cur = ks & 1;
    short8 a[MR];
    #pragma unroll
    for (int mr = 0; mr < MR; ++mr) a[mr] = *(const short8*)(arow[mr] + ks * 32);
    short8 st[CH];
    if (ks + 1 < KS) {
      const short8* src = (const short8*)(Wf + (size_t)(ks + 1) * BSZ);
      #pragma unroll
      for (int c = 0; c < CH; ++c) st[c] = src[c * 256 + j];
    }
    const bf16* wb = bs[cur] + (size_t)l * 8;
    #pragma unroll
    for (int ct = 0; ct < NT; ++ct) {
      short8 b = *(const short8*)(wb + ct * 512);
      #pragma unroll
      for (int mr = 0; mr < MR; ++mr)
        acc[mr][ct] = __builtin_amdgcn_mfma_f32_16x16x32_bf16(a[mr], b, acc[mr][ct], 0, 0, 0);
    }
    if (ks + 1 < KS) {
      short8* dst = (short8*)bs[cur ^ 1];
      #pragma unroll
      for (int c = 0; c < CH; ++c) dst[c * 256 + j] = st[c];
    }
    __syncthreads();
  }

  #pragma unroll
  for (int mr = 0; mr < MR; ++mr) {
    #pragma unroll
    for (int ct = 0; ct < NT; ++ct) {
      const float bj = bias[ct * 16 + r];
      #pragma unroll
      for (int i = 0; i < 4; ++i) acc[mr][ct][i] += bj;
    }
  }

  if (MODE == 0 || MODE == 2 || MODE == 4) {
    #pragma unroll
    for (int mr = 0; mr < MR; ++mr)
      #pragma unroll
      for (int ct = 0; ct < NT; ++ct)
        #pragma unroll
        for (int i = 0; i < 4; ++i) {
          float v = acc[mr][ct][i];
          if (MODE == 0) v = fmaxf(v, 0.f);
          size_t off = (size_t)(tile * (16 * MR) + mr * 16 + g * 4 + i) * N + ct * 16 + r;
          if (MODE == 4) ((float*)Cout)[off] = v;
          else           ((bf16*)Cout)[off]  = __float2bfloat16(v);
        }
  } else {
    #pragma unroll
    for (int mr = 0; mr < MR; ++mr) {
      float s[4] = {0.f, 0.f, 0.f, 0.f};
      #pragma unroll
      for (int ct = 0; ct < NT; ++ct)
        #pragma unroll
        for (int i = 0; i < 4; ++i) s[i] += acc[mr][ct][i] * acc[mr][ct][i];
      #pragma unroll
      for (int off = 1; off < 16; off <<= 1) {
        #pragma unroll
        for (int i = 0; i < 4; ++i) s[i] += __shfl_xor(s[i], off);
      }
      float rn[4];
      #pragma unroll
      for (int i = 0; i < 4; ++i) rn[i] = 1.f / fmaxf(sqrtf(s[i]), 1e-12f);
      #pragma unroll
      for (int ct = 0; ct < NT; ++ct)
        #pragma unroll
        for (int i = 0; i < 4; ++i) {
          size_t off = (size_t)(tile * (16 * MR) + mr * 16 + g * 4 + i) * N + ct * 16 + r;
          float v = acc[mr][ct][i] * rn[i];
          if (MODE == 3) ((float*)Cout)[off] = v;
          else           ((bf16*)Cout)[off]  = __float2bfloat16(v);
        }
    }
  }
}

// ---------------------------------------------------------------------------
// Attention v7-fp8: 16-lane row groups, no-max softmax (|s|<0.1 by
// construction), fp8 e4m3 embeddings (one 16B load/lane/row).
// ---------------------------------------------------------------------------
__global__ __launch_bounds__(256) void k_user_attn(
    const float* __restrict__ Qt,          // [NUSERS][TOW] fp32 (Wqk-folded)
    const int*   __restrict__ hist_idx,
    const int*   __restrict__ hist_len,
    const unsigned char* __restrict__ emb8,// [rows][TOW] fp8 e4m3 (normalized)
    bf16* __restrict__ fused)
{
  const int u = blockIdx.x;
  const int j = threadIdx.x;
  const int wid = j >> 6, lane = j & 63;
  const int g = lane >> 4, r = lane & 15;
  const int part = wid * 4 + g;
  __shared__ int   idx[HLEN];
  __shared__ float redO[16][TOW + 4];
  __shared__ float redL[16];

  const int nv = hist_len[u] + 1;

  if (j < HLEN) idx[j] = hist_idx[u * HLEN + j];
  const float* qp = Qt + (size_t)u * TOW + r * 16;
  f32x4 q0 = *(const f32x4*)(qp);
  f32x4 q1 = *(const f32x4*)(qp + 4);
  f32x4 q2 = *(const f32x4*)(qp + 8);
  f32x4 q3 = *(const f32x4*)(qp + 12);
  __syncthreads();

  float l = 0.f;
  f32x4 O0 = (f32x4){0.f,0.f,0.f,0.f}, O1 = O0, O2 = O0, O3 = O0;

  for (int h = part; h < nv; h += 16) {
    const uchar16 e = *(const uchar16*)(emb8 + (size_t)idx[h] * TOW + r * 16);
    float ef[16];
    #pragma unroll
    for (int i = 0; i < 16; ++i) ef[i] = e4m3f(e[i]);

    float sc = q0.x*ef[0] + q0.y*ef[1] + q0.z*ef[2] + q0.w*ef[3]
             + q1.x*ef[4] + q1.y*ef[5] + q1.z*ef[6] + q1.w*ef[7]
             + q2.x*ef[8] + q2.y*ef[9] + q2.z*ef[10]+ q2.w*ef[11]
             + q3.x*ef[12]+ q3.y*ef[13]+ q3.z*ef[14]+ q3.w*ef[15];
    #pragma unroll
    for (int off = 1; off < 16; off <<= 1) sc += __shfl_xor(sc, off);
    const float p = __expf(sc);
    l += p;
    O0.x += p*ef[0];  O0.y += p*ef[1];  O0.z += p*ef[2];  O0.w += p*ef[3];
    O1.x += p*ef[4];  O1.y += p*ef[5];  O1.z += p*ef[6];  O1.w += p*ef[7];
    O2.x += p*ef[8];  O2.y += p*ef[9];  O2.z += p*ef[10]; O2.w += p*ef[11];
    O3.x += p*ef[12]; O3.y += p*ef[13]; O3.z += p*ef[14]; O3.w += p*ef[15];
  }

  *(f32x4*)(&redO[part][r * 16])      = O0;
  *(f32x4*)(&redO[part][r * 16 + 4])  = O1;
  *(f32x4*)(&redO[part][r * 16 + 8])  = O2;
  *(f32x4*)(&redO[part][r * 16 + 12]) = O3;
  if (r == 0) redL[part] = l;
  __syncthreads();

  float L = 0.f, val = 0.f;
  #pragma unroll
  for (int w = 0; w < 16; ++w) {
    L   += redL[w];
    val += redO[w][j];
  }
  fused[(size_t)u * (GCN + TOW) + GCN + j] = __float2bfloat16(val / L);
}

// ---------------------------------------------------------------------------
extern "C" void kernel_launch(void* const* d_in, const int* in_sizes, int n_in,
                              void* d_out, int out_size, void* d_ws, size_t ws_size,
                              hipStream_t stream) {
  const float* item_feat = (const float*)d_in[0];
  const float* gcn_item  = (const float*)d_in[1];
  const float* gcn_user  = (const float*)d_in[2];
  const int*   hist_idx  = (const int*)d_in[3];
  const int*   hist_len  = (const int*)d_in[4];
  const float* Wi1 = (const float*)d_in[5];
  const float* bi1 = (const float*)d_in[6];
  const float* Wi2 = (const float*)d_in[7];
  const float* bi2 = (const float*)d_in[8];
  const float* Wq  = (const float*)d_in[9];
  const float* bq  = (const float*)d_in[10];
  const float* Wk  = (const float*)d_in[11];
  const float* bk  = (const float*)d_in[12];  // cancels in softmax
  const float* Wu1 = (const float*)d_in[13];
  const float* bu1 = (const float*)d_in[14];
  const float* Wu2 = (const float*)d_in[15];
  const float* bu2 = (const float*)d_in[16];
  (void)bk;

  char* ws = (char*)d_ws;
  bf16*  Wi1p  = (bf16*)(ws + 0);            // 81,920 B
  unsigned char* Wi2p8 = (unsigned char*)(ws + 81920);  // 65,536 -> 147,456
  bf16*  Wu1p  = (bf16*)(ws + 147456);       // 196,608 -> 344,064
  bf16*  Wu2p  = (bf16*)(ws + 344064);       // 131,072 -> 475,136
  float* Wqkf  = (float*)(ws + 475136);      // 132,096 -> 607,232
  bf16*  Wqkp  = (bf16*)(ws + 607232);       // 65,536 -> 672,768
  float* Qt    = (float*)(ws + 672768);      // 16,777,216 -> 17,449,984
  unsigned char* h8   = (unsigned char*)(ws + 17449984); // 100,096*256 -> 43,074,560
  unsigned char* emb8 = (unsigned char*)(ws + 43074560); // 100,096*256 -> 68,699,136
  bf16*  fusedA   = (bf16*)(ws + 68699136);  // 12,582,912 -> 81,282,048
  bf16*  hu_buf   = (bf16*)(ws + 81282048);  // 8,388,608 -> 89,670,656

  // ---- packing / folding ----
  k_prep_w<<<160, 256, 0, stream>>>(Wi1, Wi1p, 130, 5, 16, 1);   // permuted (gcn-first)
  k_prep_w8<<<256, 256, 0, stream>>>(Wi2, Wi2p8, 8, 16);
  k_prep_w<<<384, 256, 0, stream>>>(Wu1, Wu1p, 384, 12, 16, 0);
  k_prep_w<<<256, 256, 0, stream>>>(Wu2, Wu2p, 256, 8, 16, 0);
  k_fold<<<17, 256, 0, stream>>>(Wq, Wk, bq, Wqkf);
  k_prep_w<<<128, 256, 0, stream>>>(Wqkf, Wqkp, 128, 4, 16, 0);
  k_prep_user<<<8192, 256, 0, stream>>>(gcn_user, fusedA);

  // ---- item tower ----
  const int i128 = (NITEMS + 127) / 128;     // 782 (128-row tiles)
  k_item_g1<<<512, 512, 0, stream>>>(item_feat, gcn_item, Wi1p, Wi1, bi1, h8, i128);
  k_gemm2_f8<<<512, 512, 0, stream>>>(h8, Wi2p8, bi2, emb8, i128);

  // ---- user tower ----
  const int utiles = NUSERS / 32;            // 512
  const int ublk = utiles / 4;               // 128
  k_gemm<4, 16, 4, 2><<<ublk, 256, 0, stream>>>(fusedA, Wqkp, Wqkf + 128 * 256, Qt, utiles, 384);
  k_user_attn<<<NUSERS, 256, 0, stream>>>(Qt, hist_idx, hist_len, emb8, fusedA);
  k_gemm<12, 16, 0, 2><<<ublk, 256, 0, stream>>>(fusedA, Wu1p, bu1, hu_buf, utiles, 384);
  k_gemm<8, 16, 3, 2><<<ublk, 256, 0, stream>>>(hu_buf, Wu2p, bu2, (float*)d_out, utiles, 256);
}

// Round 24
// 141.953 us; speedup vs baseline: 3.2854x; 1.0473x over previous
//
#include <hip/hip_runtime.h>
#include <hip/hip_bf16.h>
#include <hip/hip_fp8.h>
#include <math.h>

#define NITEMS 100000
#define NUSERS 16384
#define HLEN   48
#define GCN    128
#define ATTN_D 128
#define HID    256
#define TOW    256

typedef __attribute__((ext_vector_type(8))) short short8;
typedef __attribute__((ext_vector_type(16))) unsigned char uchar16;
typedef __attribute__((ext_vector_type(4))) float f32x4;
typedef __hip_bfloat16 bf16;

static __device__ __forceinline__ float bfu(unsigned short u) {
  unsigned int x = ((unsigned int)u) << 16;
  float f; __builtin_memcpy(&f, &x, 4); return f;
}
static __device__ __forceinline__ short f2bf(float v) {
  bf16 h = __float2bfloat16(v);
  short s; __builtin_memcpy(&s, &h, 2); return s;
}
static __device__ __forceinline__ unsigned char f2e4m3(float v) {
  __hip_fp8_e4m3 t(v);
  return (unsigned char)t.__x;
}
static __device__ __forceinline__ float e4m3f(unsigned char b) {
  __hip_fp8_e4m3 t;
  t.__x = (__hip_fp8_storage_t)b;
  return (float)t;
}

// global->LDS direct copy, 16B per lane; lds dest = wave-uniform base + lane*16
#define GLDS16(g, l)                                                            \
  __builtin_amdgcn_global_load_lds(                                             \
      (const __attribute__((address_space(1))) unsigned int*)(g),               \
      (__attribute__((address_space(3))) unsigned int*)(l), 16, 0, 0)

// ---------------------------------------------------------------------------
// Prep: pack fp32 weight [Korig][N] -> bf16 fragment-ordered buffer.
// perm=1: source row permuted gcn-first (srck = k<128 ? k+2 : k-128).
// ---------------------------------------------------------------------------
__global__ __launch_bounds__(256) void k_prep_w(const float* __restrict__ W,
                                                bf16* __restrict__ out,
                                                int Korig, int KS, int NT, int perm) {
  int tid = blockIdx.x * 256 + threadIdx.x;
  int total = KS * NT * 512;
  if (tid >= total) return;
  int i  = tid & 7;
  int l  = (tid >> 3) & 63;
  int ct = (tid >> 9) % NT;
  int ks = (tid >> 9) / NT;
  int k   = ks * 32 + ((l >> 4) << 3) + i;
  int col = ct * 16 + (l & 15);
  int N = NT * 16;
  int srck = perm ? ((k < 128) ? (k + 2) : (k - 128)) : k;
  float v = (k < Korig) ? W[(size_t)srck * N + col] : 0.f;
  out[tid] = __float2bfloat16(v);
}

// Same fragment order but fp8 e4m3 output (for the fp8 MFMA GEMM2 B operand).
__global__ __launch_bounds__(256) void k_prep_w8(const float* __restrict__ W,
                                                 unsigned char* __restrict__ out,
                                                 int KS, int NT) {
  int tid = blockIdx.x * 256 + threadIdx.x;
  int total = KS * NT * 512;
  if (tid >= total) return;
  int i  = tid & 7;
  int l  = (tid >> 3) & 63;
  int ct = (tid >> 9) % NT;
  int ks = (tid >> 9) / NT;
  int k   = ks * 32 + ((l >> 4) << 3) + i;
  int col = ct * 16 + (l & 15);
  out[tid] = f2e4m3(W[(size_t)k * (NT * 16) + col]);
}

__global__ __launch_bounds__(256) void k_prep_user(const float* __restrict__ gcn_user,
                                                   bf16* __restrict__ fused) {
  int tid = blockIdx.x * 256 + threadIdx.x;
  if (tid >= NUSERS * GCN) return;
  int k = tid & 127;
  int u = tid >> 7;
  fused[(size_t)u * (GCN + TOW) + k] = __float2bfloat16(gcn_user[tid]);
}

// ---------------------------------------------------------------------------
// Fold: Wqk[g][t] = (1/sqrt(128)) * sum_d Wq[g][d] * Wk[t][d]   (g<128)
//       b~[t]    = (1/sqrt(128)) * sum_d bq[d]    * Wk[t][d]    (block 16)
// ---------------------------------------------------------------------------
__global__ __launch_bounds__(256) void k_fold(const float* __restrict__ Wq,
                                              const float* __restrict__ Wk,
                                              const float* __restrict__ bq,
                                              float* __restrict__ out) {
  const float INV_S = 0.08838834764831845f;
  const int t = threadIdx.x;
  const int b = blockIdx.x;
  if (b < 16) {
    __shared__ float wq[8][128];
    for (int s = t; s < 8 * 128; s += 256)
      wq[s >> 7][s & 127] = Wq[(size_t)(b * 8 + (s >> 7)) * ATTN_D + (s & 127)];
    __syncthreads();
    float acc[8] = {0.f, 0.f, 0.f, 0.f, 0.f, 0.f, 0.f, 0.f};
    for (int d = 0; d < 128; ++d) {
      const float wk = Wk[(size_t)t * ATTN_D + d];
      #pragma unroll
      for (int gg = 0; gg < 8; ++gg) acc[gg] = fmaf(wq[gg][d], wk, acc[gg]);
    }
    #pragma unroll
    for (int gg = 0; gg < 8; ++gg)
      out[(size_t)(b * 8 + gg) * TOW + t] = acc[gg] * INV_S;
  } else {
    float a = 0.f;
    for (int d = 0; d < 128; ++d)
      a = fmaf(bq[d], Wk[(size_t)t * ATTN_D + d], a);
    out[(size_t)128 * TOW + t] = a * INV_S;
  }
}

// ---------------------------------------------------------------------------
// Item GEMM1 v2: h8 = fp8(relu(gcn@W1gcn + feat-rank2 + b1)).
// MFMA loop covers only the gcn K=128 (ks=0..3, 64KB persistent LDS B);
// feat rank-2 applied in the epilogue as fp32 FMAs (Wi1 rows 0,1 in LDS).
// MR=1, 128-row tiles, launch_bounds(512,4) -> 4 waves/SIMD, 2 blocks/CU.
// ---------------------------------------------------------------------------
__global__ __launch_bounds__(512, 4) void k_item_g1(
    const float* __restrict__ feat,
    const float* __restrict__ gcn,
    const bf16* __restrict__ Wf,      // packed KS=5 (ks=0..3 used), perm gcn-first
    const float* __restrict__ Wi1raw, // original fp32 Wi1 [130][256]
    const float* __restrict__ bias,
    unsigned char* __restrict__ h_out, // fp8 e4m3
    int ntiles)
{
  __shared__ bf16  bs[4 * 8192];      // 64 KB = gcn part of W1p
  __shared__ float wfeat[512];        // Wi1 rows 0,1 (fp32)
  const int j = threadIdx.x;
  const int l = j & 63;
  const int w = j >> 6;               // 0..7 row-wave
  const int r = l & 15, g = l >> 4;
  const int jb = (j & ~63) * 8;

  #pragma unroll
  for (int s = 0; s < 8; ++s)
    GLDS16(Wf + (size_t)s * 4096 + (size_t)j * 8, &bs[s * 4096 + jb]);
  wfeat[j] = Wi1raw[j];

  float bj[16];
  #pragma unroll
  for (int ct = 0; ct < 16; ++ct) bj[ct] = bias[ct * 16 + r];

  __syncthreads();   // only barrier

  for (int t = blockIdx.x; t < ntiles; t += gridDim.x) {
    const int R0 = t * 128 + w * 16;
    int arow = R0 + r; if (arow >= NITEMS) arow = NITEMS - 1;
    const float* grow = gcn + (size_t)arow * GCN;

    f32x4 acc[16];
    #pragma unroll
    for (int ct = 0; ct < 16; ++ct) acc[ct] = (f32x4){0.f, 0.f, 0.f, 0.f};

    #pragma unroll 1
    for (int ks = 0; ks < 4; ++ks) {
      const float4* p = (const float4*)(grow + ks * 32 + g * 8);
      float4 x = p[0], y = p[1];
      short8 a;
      a[0] = f2bf(x.x); a[1] = f2bf(x.y); a[2] = f2bf(x.z); a[3] = f2bf(x.w);
      a[4] = f2bf(y.x); a[5] = f2bf(y.y); a[6] = f2bf(y.z); a[7] = f2bf(y.w);
      const bf16* wb = bs + (size_t)(ks * 16) * 512 + (size_t)l * 8;
      #pragma unroll
      for (int ct = 0; ct < 16; ++ct) {
        short8 b = *(const short8*)(wb + ct * 512);
        acc[ct] = __builtin_amdgcn_mfma_f32_16x16x32_bf16(a, b, acc[ct], 0, 0, 0);
      }
    }

    // epilogue: feat rank-2 + bias + relu -> fp8 (lane rows R0+g*4+i)
    float f0[4], f1[4];
    #pragma unroll
    for (int i = 0; i < 4; ++i) {
      int orow = R0 + g * 4 + i; if (orow >= NITEMS) orow = NITEMS - 1;
      float2 fv = *(const float2*)(feat + (size_t)orow * 2);
      f0[i] = fv.x; f1[i] = fv.y;
    }
    #pragma unroll
    for (int ct = 0; ct < 16; ++ct) {
      const float w0 = wfeat[ct * 16 + r];
      const float w1 = wfeat[256 + ct * 16 + r];
      #pragma unroll
      for (int i = 0; i < 4; ++i) {
        float v = acc[ct][i] + bj[ct];
        v = fmaf(f0[i], w0, v);
        v = fmaf(f1[i], w1, v);
        h_out[(size_t)(R0 + g * 4 + i) * 256 + ct * 16 + r] =
            f2e4m3(fmaxf(v, 0.f));
      }
    }
  }
}

// ---------------------------------------------------------------------------
// GEMM2 in fp8: emb8 = fp8(l2norm(h8 @ W2f8 + b2)).
// Persistent fp8 B = 64KB LDS -> 2 blocks/CU; launch_bounds(512,4).
// ---------------------------------------------------------------------------
__global__ __launch_bounds__(512, 4) void k_gemm2_f8(
    const unsigned char* __restrict__ A8,   // [rows][256] fp8 (h)
    const unsigned char* __restrict__ Wf8,  // packed KS=8, NT=16, fp8
    const float* __restrict__ bias,
    unsigned char* __restrict__ Cout,       // [rows][256] fp8 (emb)
    int ntiles)
{
  __shared__ unsigned char bs8[8 * 8192];   // 64 KB = full fp8 B
  const int j = threadIdx.x;
  const int l = j & 63;
  const int w = j >> 6;               // 0..7 row-wave
  const int r = l & 15, g = l >> 4;
  const int jb = (j & ~63) * 16;      // wave-uniform LDS byte base

  #pragma unroll
  for (int s = 0; s < 8; ++s)
    GLDS16(Wf8 + (size_t)s * 8192 + (size_t)j * 16, &bs8[s * 8192 + jb]);

  __syncthreads();   // only barrier

  for (int t = blockIdx.x; t < ntiles; t += gridDim.x) {
    const int R0 = t * 128 + w * 16;
    const unsigned char* arow = A8 + (size_t)(R0 + r) * 256 + g * 8;
    const unsigned char* wbase = bs8 + (size_t)l * 8;

    f32x4 acc[16];
    #pragma unroll
    for (int ct = 0; ct < 16; ++ct) acc[ct] = (f32x4){0.f, 0.f, 0.f, 0.f};

    #pragma unroll 1
    for (int ks = 0; ks < 8; ++ks) {
      long a;
      __builtin_memcpy(&a, arow + ks * 32, 8);
      const unsigned char* wb = wbase + (size_t)(ks * 16) * 512;
      #pragma unroll
      for (int ct = 0; ct < 16; ++ct) {
        long b;
        __builtin_memcpy(&b, wb + ct * 512, 8);
        acc[ct] = __builtin_amdgcn_mfma_f32_16x16x32_fp8_fp8(a, b, acc[ct], 0, 0, 0);
      }
    }

    float s[4] = {0.f, 0.f, 0.f, 0.f};
    #pragma unroll
    for (int ct = 0; ct < 16; ++ct) {
      const float bj = bias[ct * 16 + r];
      #pragma unroll
      for (int i = 0; i < 4; ++i) {
        acc[ct][i] += bj;
        s[i] += acc[ct][i] * acc[ct][i];
      }
    }
    #pragma unroll
    for (int off = 1; off < 16; off <<= 1) {
      #pragma unroll
      for (int i = 0; i < 4; ++i) s[i] += __shfl_xor(s[i], off);
    }
    float rn[4];
    #pragma unroll
    for (int i = 0; i < 4; ++i) rn[i] = 1.f / fmaxf(sqrtf(s[i]), 1e-12f);
    #pragma unroll
    for (int ct = 0; ct < 16; ++ct)
      #pragma unroll
      for (int i = 0; i < 4; ++i)
        Cout[(size_t)(R0 + g * 4 + i) * 256 + ct * 16 + r] =
            f2e4m3(acc[ct][i] * rn[i]);
  }
}

// ---------------------------------------------------------------------------
// Generic MFMA GEMM (user tower), LDS-staged double-buffered B, 4 waves.
// MODE 0: relu->bf16; 3: l2norm->fp32; 4: plain->fp32
// ---------------------------------------------------------------------------
template<int KS, int NT, int MODE, int MR>
__global__ __launch_bounds__(256) void k_gemm(
    const bf16* __restrict__ A,
    const bf16* __restrict__ Wf,
    const float* __restrict__ bias,
    void* __restrict__ Cout,
    int Mtiles, int Astride)
{
  static_assert(NT % 4 == 0, "NT must be divisible by 4");
  constexpr int BSZ = NT * 512;
  constexpr int CH  = NT / 4;
  __shared__ bf16 bs[2][BSZ];
  const int j   = threadIdx.x;
  const int l   = j & 63;
  const int wid = j >> 6;
  int tile = blockIdx.x * 4 + wid;
  if (tile >= Mtiles) tile = Mtiles - 1;
  const int N = NT * 16;
  const int r = l & 15, g = l >> 4;

  {
    const short8* src = (const short8*)Wf;
    short8* dst = (short8*)bs[0];
    #pragma unroll
    for (int c = 0; c < CH; ++c) dst[c * 256 + j] = src[c * 256 + j];
  }

  f32x4 acc[MR][NT];
  #pragma unroll
  for (int mr = 0; mr < MR; ++mr)
    #pragma unroll
    for (int ct = 0; ct < NT; ++ct) acc[mr][ct] = (f32x4){0.f, 0.f, 0.f, 0.f};

  const bf16* arow[MR];
  #pragma unroll
  for (int mr = 0; mr < MR; ++mr)
    arow[mr] = A + (size_t)(tile * (16 * MR) + mr * 16 + r) * Astride + g * 8;

  __syncthreads();

  #pragma unroll
  for (int ks = 0; ks < KS; ++ks) {
    const int cur = ks & 1;
    short8 a[MR];
    #pragma unroll
    for (int mr = 0; mr < MR; ++mr) a[mr] = *(const short8*)(arow[mr] + ks * 32);
    short8 st[CH];
    if (ks + 1 < KS) {
      const short8* src = (const short8*)(Wf + (size_t)(ks + 1) * BSZ);
      #pragma unroll
      for (int c = 0; c < CH; ++c) st[c] = src[c * 256 + j];
    }
    const bf16* wb = bs[cur] + (size_t)l * 8;
    #pragma unroll
    for (int ct = 0; ct < NT; ++ct) {
      short8 b = *(const short8*)(wb + ct * 512);
      #pragma unroll
      for (int mr = 0; mr < MR; ++mr)
        acc[mr][ct] = __builtin_amdgcn_mfma_f32_16x16x32_bf16(a[mr], b, acc[mr][ct], 0, 0, 0);
    }
    if (ks + 1 < KS) {
      short8* dst = (short8*)bs[cur ^ 1];
      #pragma unroll
      for (int c = 0; c < CH; ++c) dst[c * 256 + j] = st[c];
    }
    __syncthreads();
  }

  #pragma unroll
  for (int mr = 0; mr < MR; ++mr) {
    #pragma unroll
    for (int ct = 0; ct < NT; ++ct) {
      const float bj = bias[ct * 16 + r];
      #pragma unroll
      for (int i = 0; i < 4; ++i) acc[mr][ct][i] += bj;
    }
  }

  if (MODE == 0 || MODE == 2 || MODE == 4) {
    #pragma unroll
    for (int mr = 0; mr < MR; ++mr)
      #pragma unroll
      for (int ct = 0; ct < NT; ++ct)
        #pragma unroll
        for (int i = 0; i < 4; ++i) {
          float v = acc[mr][ct][i];
          if (MODE == 0) v = fmaxf(v, 0.f);
          size_t off = (size_t)(tile * (16 * MR) + mr * 16 + g * 4 + i) * N + ct * 16 + r;
          if (MODE == 4) ((float*)Cout)[off] = v;
          else           ((bf16*)Cout)[off]  = __float2bfloat16(v);
        }
  } else {
    #pragma unroll
    for (int mr = 0; mr < MR; ++mr) {
      float s[4] = {0.f, 0.f, 0.f, 0.f};
      #pragma unroll
      for (int ct = 0; ct < NT; ++ct)
        #pragma unroll
        for (int i = 0; i < 4; ++i) s[i] += acc[mr][ct][i] * acc[mr][ct][i];
      #pragma unroll
      for (int off = 1; off < 16; off <<= 1) {
        #pragma unroll
        for (int i = 0; i < 4; ++i) s[i] += __shfl_xor(s[i], off);
      }
      float rn[4];
      #pragma unroll
      for (int i = 0; i < 4; ++i) rn[i] = 1.f / fmaxf(sqrtf(s[i]), 1e-12f);
      #pragma unroll
      for (int ct = 0; ct < NT; ++ct)
        #pragma unroll
        for (int i = 0; i < 4; ++i) {
          size_t off = (size_t)(tile * (16 * MR) + mr * 16 + g * 4 + i) * N + ct * 16 + r;
          float v = acc[mr][ct][i] * rn[i];
          if (MODE == 3) ((float*)Cout)[off] = v;
          else           ((bf16*)Cout)[off]  = __float2bfloat16(v);
        }
    }
  }
}

// ---------------------------------------------------------------------------
// Attention v8: ONE USER PER WAVE — no LDS, no barriers. 4 groups of 16
// lanes split the rows (h = g, g+4, ...); in-group shfl dot-reduce; no-max
// softmax (|s|<0.1 by construction); group partials merged in-register via
// shfl_xor(16,32); g==0 lanes store 2x short8 (coalesced).
// ---------------------------------------------------------------------------
__global__ __launch_bounds__(256) void k_user_attn(
    const float* __restrict__ Qt,          // [NUSERS][TOW] fp32 (Wqk-folded)
    const int*   __restrict__ hist_idx,
    const int*   __restrict__ hist_len,
    const unsigned char* __restrict__ emb8,// [rows][TOW] fp8 e4m3 (normalized)
    bf16* __restrict__ fused)
{
  const int wid = threadIdx.x >> 6, lane = threadIdx.x & 63;
  const int u = blockIdx.x * 4 + wid;
  const int g = lane >> 4, r = lane & 15;
  const int nv = hist_len[u] + 1;          // 1..48 valid rows
  const int* uidx = hist_idx + (size_t)u * HLEN;

  const float* qp = Qt + (size_t)u * TOW + r * 16;
  f32x4 q0 = *(const f32x4*)(qp);
  f32x4 q1 = *(const f32x4*)(qp + 4);
  f32x4 q2 = *(const f32x4*)(qp + 8);
  f32x4 q3 = *(const f32x4*)(qp + 12);

  float l = 0.f;
  f32x4 O0 = (f32x4){0.f,0.f,0.f,0.f}, O1 = O0, O2 = O0, O3 = O0;

  int h = g;
  uchar16 e = (uchar16){0,0,0,0,0,0,0,0,0,0,0,0,0,0,0,0};
  if (h < nv)
    e = *(const uchar16*)(emb8 + (size_t)uidx[h] * TOW + r * 16);
  for (; h < nv; h += 4) {
    uchar16 en = (uchar16){0,0,0,0,0,0,0,0,0,0,0,0,0,0,0,0};
    if (h + 4 < nv)
      en = *(const uchar16*)(emb8 + (size_t)uidx[h + 4] * TOW + r * 16);
    float ef[16];
    #pragma unroll
    for (int i = 0; i < 16; ++i) ef[i] = e4m3f(e[i]);

    float sc = q0.x*ef[0] + q0.y*ef[1] + q0.z*ef[2] + q0.w*ef[3]
             + q1.x*ef[4] + q1.y*ef[5] + q1.z*ef[6] + q1.w*ef[7]
             + q2.x*ef[8] + q2.y*ef[9] + q2.z*ef[10]+ q2.w*ef[11]
             + q3.x*ef[12]+ q3.y*ef[13]+ q3.z*ef[14]+ q3.w*ef[15];
    // reduce within the 16-lane group (xor 1,2,4,8 stay in-group)
    #pragma unroll
    for (int off = 1; off < 16; off <<= 1) sc += __shfl_xor(sc, off);
    const float p = __expf(sc);
    l += p;
    O0.x += p*ef[0];  O0.y += p*ef[1];  O0.z += p*ef[2];  O0.w += p*ef[3];
    O1.x += p*ef[4];  O1.y += p*ef[5];  O1.z += p*ef[6];  O1.w += p*ef[7];
    O2.x += p*ef[8];  O2.y += p*ef[9];  O2.z += p*ef[10]; O2.w += p*ef[11];
    O3.x += p*ef[12]; O3.y += p*ef[13]; O3.z += p*ef[14]; O3.w += p*ef[15];
    e = en;
  }

  // merge the 4 group partials in-register (same dims, disjoint rows)
  #pragma unroll
  for (int off = 16; off < 64; off <<= 1) {
    l += __shfl_xor(l, off);
    #pragma unroll
    for (int i = 0; i < 4; ++i) {
      O0[i] += __shfl_xor(O0[i], off);
      O1[i] += __shfl_xor(O1[i], off);
      O2[i] += __shfl_xor(O2[i], off);
      O3[i] += __shfl_xor(O3[i], off);
    }
  }

  if (g == 0) {
    const float inv = 1.f / l;
    short8 o0, o1;
    #pragma unroll
    for (int i = 0; i < 4; ++i) {
      o0[i]     = f2bf(O0[i] * inv);
      o0[4 + i] = f2bf(O1[i] * inv);
      o1[i]     = f2bf(O2[i] * inv);
      o1[4 + i] = f2bf(O3[i] * inv);
    }
    bf16* dst = fused + (size_t)u * (GCN + TOW) + GCN + r * 16;
    *(short8*)dst       = o0;
    *(short8*)(dst + 8) = o1;
  }
}

// ---------------------------------------------------------------------------
extern "C" void kernel_launch(void* const* d_in, const int* in_sizes, int n_in,
                              void* d_out, int out_size, void* d_ws, size_t ws_size,
                              hipStream_t stream) {
  const float* item_feat = (const float*)d_in[0];
  const float* gcn_item  = (const float*)d_in[1];
  const float* gcn_user  = (const float*)d_in[2];
  const int*   hist_idx  = (const int*)d_in[3];
  const int*   hist_len  = (const int*)d_in[4];
  const float* Wi1 = (const float*)d_in[5];
  const float* bi1 = (const float*)d_in[6];
  const float* Wi2 = (const float*)d_in[7];
  const float* bi2 = (const float*)d_in[8];
  const float* Wq  = (const float*)d_in[9];
  const float* bq  = (const float*)d_in[10];
  const float* Wk  = (const float*)d_in[11];
  const float* bk  = (const float*)d_in[12];  // cancels in softmax
  const float* Wu1 = (const float*)d_in[13];
  const float* bu1 = (const float*)d_in[14];
  const float* Wu2 = (const float*)d_in[15];
  const float* bu2 = (const float*)d_in[16];
  (void)bk;

  char* ws = (char*)d_ws;
  bf16*  Wi1p  = (bf16*)(ws + 0);            // 81,920 B
  unsigned char* Wi2p8 = (unsigned char*)(ws + 81920);  // 65,536 -> 147,456
  bf16*  Wu1p  = (bf16*)(ws + 147456);       // 196,608 -> 344,064
  bf16*  Wu2p  = (bf16*)(ws + 344064);       // 131,072 -> 475,136
  float* Wqkf  = (float*)(ws + 475136);      // 132,096 -> 607,232
  bf16*  Wqkp  = (bf16*)(ws + 607232);       // 65,536 -> 672,768
  float* Qt    = (float*)(ws + 672768);      // 16,777,216 -> 17,449,984
  unsigned char* h8   = (unsigned char*)(ws + 17449984); // 100,096*256 -> 43,074,560
  unsigned char* emb8 = (unsigned char*)(ws + 43074560); // 100,096*256 -> 68,699,136
  bf16*  fusedA   = (bf16*)(ws + 68699136);  // 12,582,912 -> 81,282,048
  bf16*  hu_buf   = (bf16*)(ws + 81282048);  // 8,388,608 -> 89,670,656

  // ---- packing / folding ----
  k_prep_w<<<160, 256, 0, stream>>>(Wi1, Wi1p, 130, 5, 16, 1);   // permuted (gcn-first)
  k_prep_w8<<<256, 256, 0, stream>>>(Wi2, Wi2p8, 8, 16);
  k_prep_w<<<384, 256, 0, stream>>>(Wu1, Wu1p, 384, 12, 16, 0);
  k_prep_w<<<256, 256, 0, stream>>>(Wu2, Wu2p, 256, 8, 16, 0);
  k_fold<<<17, 256, 0, stream>>>(Wq, Wk, bq, Wqkf);
  k_prep_w<<<128, 256, 0, stream>>>(Wqkf, Wqkp, 128, 4, 16, 0);
  k_prep_user<<<8192, 256, 0, stream>>>(gcn_user, fusedA);

  // ---- item tower ----
  const int i128 = (NITEMS + 127) / 128;     // 782 (128-row tiles)
  k_item_g1<<<512, 512, 0, stream>>>(item_feat, gcn_item, Wi1p, Wi1, bi1, h8, i128);
  k_gemm2_f8<<<512, 512, 0, stream>>>(h8, Wi2p8, bi2, emb8, i128);

  // ---- user tower ----
  const int utiles = NUSERS / 32;            // 512
  const int ublk = utiles / 4;               // 128
  k_gemm<4, 16, 4, 2><<<ublk, 256, 0, stream>>>(fusedA, Wqkp, Wqkf + 128 * 256, Qt, utiles, 384);
  k_user_attn<<<NUSERS / 4, 256, 0, stream>>>(Qt, hist_idx, hist_len, emb8, fusedA);
  k_gemm<12, 16, 0, 2><<<ublk, 256, 0, stream>>>(fusedA, Wu1p, bu1, hu_buf, utiles, 384);
  k_gemm<8, 16, 3, 2><<<ublk, 256, 0, stream>>>(hu_buf, Wu2p, bu2, (float*)d_out, utiles, 256);
}

// Round 25
// 121.930 us; speedup vs baseline: 3.8249x; 1.1642x over previous
//
#include <hip/hip_runtime.h>
#include <hip/hip_bf16.h>
#include <hip/hip_fp8.h>
#include <math.h>

#define NITEMS 100000
#define NUSERS 16384
#define HLEN   48
#define GCN    128
#define ATTN_D 128
#define HID    256
#define TOW    256

typedef __attribute__((ext_vector_type(8))) short short8;
typedef __attribute__((ext_vector_type(16))) unsigned char uchar16;
typedef __attribute__((ext_vector_type(4))) float f32x4;
typedef __hip_bfloat16 bf16;

static __device__ __forceinline__ float bfu(unsigned short u) {
  unsigned int x = ((unsigned int)u) << 16;
  float f; __builtin_memcpy(&f, &x, 4); return f;
}
static __device__ __forceinline__ short f2bf(float v) {
  bf16 h = __float2bfloat16(v);
  short s; __builtin_memcpy(&s, &h, 2); return s;
}
static __device__ __forceinline__ unsigned char f2e4m3(float v) {
  __hip_fp8_e4m3 t(v);
  return (unsigned char)t.__x;
}
static __device__ __forceinline__ float e4m3f(unsigned char b) {
  __hip_fp8_e4m3 t;
  t.__x = (__hip_fp8_storage_t)b;
  return (float)t;
}

// global->LDS direct copy, 16B per lane; lds dest = wave-uniform base + lane*16
#define GLDS16(g, l)                                                            \
  __builtin_amdgcn_global_load_lds(                                             \
      (const __attribute__((address_space(1))) unsigned int*)(g),               \
      (__attribute__((address_space(3))) unsigned int*)(l), 16, 0, 0)

// ---------------------------------------------------------------------------
// Fused prep: ALL weight packing + inline Wqk fold + user input cast, one
// launch, block-range dispatch. Segments (256-thr blocks):
//   [0,160)      Wi1p  bf16 pack, perm gcn-first (Korig=130, KS=5)
//   [160,416)    Wi2p8 fp8 pack (KS=8)
//   [416,800)    Wu1p  bf16 pack (Korig=384, KS=12)
//   [800,1056)   Wu2p  bf16 pack (Korig=256, KS=8)
//   [1056,1184)  Wqkp  bf16 pack with INLINE fold (same fmaf order as before)
//   [1184]       b~ bias (256 dots, fp32)
//   [1185,9377)  fused[u][0..127] = bf16(gcn_user)
// ---------------------------------------------------------------------------
static __device__ __forceinline__ void packw_bf16(
    const float* __restrict__ W, bf16* __restrict__ out,
    int tid, int Korig, int NT, int perm) {
  int i  = tid & 7;
  int l  = (tid >> 3) & 63;
  int ct = (tid >> 9) % NT;
  int ks = (tid >> 9) / NT;
  int k   = ks * 32 + ((l >> 4) << 3) + i;
  int col = ct * 16 + (l & 15);
  int N = NT * 16;
  int srck = perm ? ((k < 128) ? (k + 2) : (k - 128)) : k;
  float v = (k < Korig) ? W[(size_t)srck * N + col] : 0.f;
  out[tid] = __float2bfloat16(v);
}

__global__ __launch_bounds__(256) void k_prep_all(
    const float* __restrict__ Wi1, const float* __restrict__ Wi2,
    const float* __restrict__ Wu1, const float* __restrict__ Wu2,
    const float* __restrict__ Wq,  const float* __restrict__ Wk,
    const float* __restrict__ bq,  const float* __restrict__ gcn_user,
    bf16* __restrict__ Wi1p, unsigned char* __restrict__ Wi2p8,
    bf16* __restrict__ Wu1p, bf16* __restrict__ Wu2p,
    bf16* __restrict__ Wqkp, float* __restrict__ bqt,
    bf16* __restrict__ fused)
{
  const float INV_S = 0.08838834764831845f;
  const int b = blockIdx.x;
  const int t = threadIdx.x;
  if (b < 160) {                       // Wi1p
    packw_bf16(Wi1, Wi1p, b * 256 + t, 130, 16, 1);
  } else if (b < 416) {                // Wi2p8 (fp8)
    int tid = (b - 160) * 256 + t;
    int i  = tid & 7;
    int l  = (tid >> 3) & 63;
    int ct = (tid >> 9) % 16;
    int ks = (tid >> 9) / 16;
    int k   = ks * 32 + ((l >> 4) << 3) + i;
    int col = ct * 16 + (l & 15);
    Wi2p8[tid] = f2e4m3(Wi2[(size_t)k * 256 + col]);
  } else if (b < 800) {                // Wu1p
    packw_bf16(Wu1, Wu1p, (b - 416) * 256 + t, 384, 16, 0);
  } else if (b < 1056) {               // Wu2p
    packw_bf16(Wu2, Wu2p, (b - 800) * 256 + t, 256, 16, 0);
  } else if (b < 1184) {               // Wqkp with inline fold
    int tid = (b - 1056) * 256 + t;
    int i  = tid & 7;
    int l  = (tid >> 3) & 63;
    int ct = (tid >> 9) % 16;
    int ks = (tid >> 9) / 16;
    int k   = ks * 32 + ((l >> 4) << 3) + i;      // < 128 (KS=4)
    int col = ct * 16 + (l & 15);
    float a = 0.f;
    const float* wq = Wq + (size_t)k * ATTN_D;
    const float* wk = Wk + (size_t)col * ATTN_D;
    for (int d = 0; d < 128; ++d) a = fmaf(wq[d], wk[d], a);
    Wqkp[tid] = __float2bfloat16(a * INV_S);
  } else if (b == 1184) {              // b~ bias
    float a = 0.f;
    const float* wk = Wk + (size_t)t * ATTN_D;
    for (int d = 0; d < 128; ++d) a = fmaf(bq[d], wk[d], a);
    bqt[t] = a * INV_S;
  } else {                             // prep_user
    int tid = (b - 1185) * 256 + t;
    int k = tid & 127;
    int u = tid >> 7;
    fused[(size_t)u * (GCN + TOW) + k] = __float2bfloat16(gcn_user[tid]);
  }
}

// ---------------------------------------------------------------------------
// Item GEMM1 v2: h8 = fp8(relu(gcn@W1gcn + feat-rank2 + b1)).
// MFMA loop covers only the gcn K=128 (ks=0..3, 64KB persistent LDS B);
// feat rank-2 applied in the epilogue as fp32 FMAs (Wi1 rows 0,1 in LDS).
// MR=1, 128-row tiles, launch_bounds(512,4) -> 4 waves/SIMD, 2 blocks/CU.
// ---------------------------------------------------------------------------
__global__ __launch_bounds__(512, 4) void k_item_g1(
    const float* __restrict__ feat,
    const float* __restrict__ gcn,
    const bf16* __restrict__ Wf,      // packed KS=5 (ks=0..3 used), perm gcn-first
    const float* __restrict__ Wi1raw, // original fp32 Wi1 [130][256]
    const float* __restrict__ bias,
    unsigned char* __restrict__ h_out, // fp8 e4m3
    int ntiles)
{
  __shared__ bf16  bs[4 * 8192];      // 64 KB = gcn part of W1p
  __shared__ float wfeat[512];        // Wi1 rows 0,1 (fp32)
  const int j = threadIdx.x;
  const int l = j & 63;
  const int w = j >> 6;               // 0..7 row-wave
  const int r = l & 15, g = l >> 4;
  const int jb = (j & ~63) * 8;

  #pragma unroll
  for (int s = 0; s < 8; ++s)
    GLDS16(Wf + (size_t)s * 4096 + (size_t)j * 8, &bs[s * 4096 + jb]);
  wfeat[j] = Wi1raw[j];

  float bj[16];
  #pragma unroll
  for (int ct = 0; ct < 16; ++ct) bj[ct] = bias[ct * 16 + r];

  __syncthreads();   // only barrier

  for (int t = blockIdx.x; t < ntiles; t += gridDim.x) {
    const int R0 = t * 128 + w * 16;
    int arow = R0 + r; if (arow >= NITEMS) arow = NITEMS - 1;
    const float* grow = gcn + (size_t)arow * GCN;

    f32x4 acc[16];
    #pragma unroll
    for (int ct = 0; ct < 16; ++ct) acc[ct] = (f32x4){0.f, 0.f, 0.f, 0.f};

    #pragma unroll 1
    for (int ks = 0; ks < 4; ++ks) {
      const float4* p = (const float4*)(grow + ks * 32 + g * 8);
      float4 x = p[0], y = p[1];
      short8 a;
      a[0] = f2bf(x.x); a[1] = f2bf(x.y); a[2] = f2bf(x.z); a[3] = f2bf(x.w);
      a[4] = f2bf(y.x); a[5] = f2bf(y.y); a[6] = f2bf(y.z); a[7] = f2bf(y.w);
      const bf16* wb = bs + (size_t)(ks * 16) * 512 + (size_t)l * 8;
      #pragma unroll
      for (int ct = 0; ct < 16; ++ct) {
        short8 b = *(const short8*)(wb + ct * 512);
        acc[ct] = __builtin_amdgcn_mfma_f32_16x16x32_bf16(a, b, acc[ct], 0, 0, 0);
      }
    }

    // epilogue: feat rank-2 + bias + relu -> fp8 (lane rows R0+g*4+i)
    float f0[4], f1[4];
    #pragma unroll
    for (int i = 0; i < 4; ++i) {
      int orow = R0 + g * 4 + i; if (orow >= NITEMS) orow = NITEMS - 1;
      float2 fv = *(const float2*)(feat + (size_t)orow * 2);
      f0[i] = fv.x; f1[i] = fv.y;
    }
    #pragma unroll
    for (int ct = 0; ct < 16; ++ct) {
      const float w0 = wfeat[ct * 16 + r];
      const float w1 = wfeat[256 + ct * 16 + r];
      #pragma unroll
      for (int i = 0; i < 4; ++i) {
        float v = acc[ct][i] + bj[ct];
        v = fmaf(f0[i], w0, v);
        v = fmaf(f1[i], w1, v);
        h_out[(size_t)(R0 + g * 4 + i) * 256 + ct * 16 + r] =
            f2e4m3(fmaxf(v, 0.f));
      }
    }
  }
}

// ---------------------------------------------------------------------------
// GEMM2 in fp8: emb8 = fp8(l2norm(h8 @ W2f8 + b2)).
// Persistent fp8 B = 64KB LDS -> 2 blocks/CU; launch_bounds(512,4).
// ---------------------------------------------------------------------------
__global__ __launch_bounds__(512, 4) void k_gemm2_f8(
    const unsigned char* __restrict__ A8,   // [rows][256] fp8 (h)
    const unsigned char* __restrict__ Wf8,  // packed KS=8, NT=16, fp8
    const float* __restrict__ bias,
    unsigned char* __restrict__ Cout,       // [rows][256] fp8 (emb)
    int ntiles)
{
  __shared__ unsigned char bs8[8 * 8192];   // 64 KB = full fp8 B
  const int j = threadIdx.x;
  const int l = j & 63;
  const int w = j >> 6;               // 0..7 row-wave
  const int r = l & 15, g = l >> 4;
  const int jb = (j & ~63) * 16;      // wave-uniform LDS byte base

  #pragma unroll
  for (int s = 0; s < 8; ++s)
    GLDS16(Wf8 + (size_t)s * 8192 + (size_t)j * 16, &bs8[s * 8192 + jb]);

  __syncthreads();   // only barrier

  for (int t = blockIdx.x; t < ntiles; t += gridDim.x) {
    const int R0 = t * 128 + w * 16;
    const unsigned char* arow = A8 + (size_t)(R0 + r) * 256 + g * 8;
    const unsigned char* wbase = bs8 + (size_t)l * 8;

    f32x4 acc[16];
    #pragma unroll
    for (int ct = 0; ct < 16; ++ct) acc[ct] = (f32x4){0.f, 0.f, 0.f, 0.f};

    #pragma unroll 1
    for (int ks = 0; ks < 8; ++ks) {
      long a;
      __builtin_memcpy(&a, arow + ks * 32, 8);
      const unsigned char* wb = wbase + (size_t)(ks * 16) * 512;
      #pragma unroll
      for (int ct = 0; ct < 16; ++ct) {
        long b;
        __builtin_memcpy(&b, wb + ct * 512, 8);
        acc[ct] = __builtin_amdgcn_mfma_f32_16x16x32_fp8_fp8(a, b, acc[ct], 0, 0, 0);
      }
    }

    float s[4] = {0.f, 0.f, 0.f, 0.f};
    #pragma unroll
    for (int ct = 0; ct < 16; ++ct) {
      const float bj = bias[ct * 16 + r];
      #pragma unroll
      for (int i = 0; i < 4; ++i) {
        acc[ct][i] += bj;
        s[i] += acc[ct][i] * acc[ct][i];
      }
    }
    #pragma unroll
    for (int off = 1; off < 16; off <<= 1) {
      #pragma unroll
      for (int i = 0; i < 4; ++i) s[i] += __shfl_xor(s[i], off);
    }
    float rn[4];
    #pragma unroll
    for (int i = 0; i < 4; ++i) rn[i] = 1.f / fmaxf(sqrtf(s[i]), 1e-12f);
    #pragma unroll
    for (int ct = 0; ct < 16; ++ct)
      #pragma unroll
      for (int i = 0; i < 4; ++i)
        Cout[(size_t)(R0 + g * 4 + i) * 256 + ct * 16 + r] =
            f2e4m3(acc[ct][i] * rn[i]);
  }
}

// ---------------------------------------------------------------------------
// Generic MFMA GEMM (user tower), LDS-staged double-buffered B, 4 waves.
// MODE 0: relu->bf16; 3: l2norm->fp32; 4: plain->fp32
// ---------------------------------------------------------------------------
template<int KS, int NT, int MODE, int MR>
__global__ __launch_bounds__(256) void k_gemm(
    const bf16* __restrict__ A,
    const bf16* __restrict__ Wf,
    const float* __restrict__ bias,
    void* __restrict__ Cout,
    int Mtiles, int Astride)
{
  static_assert(NT % 4 == 0, "NT must be divisible by 4");
  constexpr int BSZ = NT * 512;
  constexpr int CH  = NT / 4;
  __shared__ bf16 bs[2][BSZ];
  const int j   = threadIdx.x;
  const int l   = j & 63;
  const int wid = j >> 6;
  int tile = blockIdx.x * 4 + wid;
  if (tile >= Mtiles) tile = Mtiles - 1;
  const int N = NT * 16;
  const int r = l & 15, g = l >> 4;

  {
    const short8* src = (const short8*)Wf;
    short8* dst = (short8*)bs[0];
    #pragma unroll
    for (int c = 0; c < CH; ++c) dst[c * 256 + j] = src[c * 256 + j];
  }

  f32x4 acc[MR][NT];
  #pragma unroll
  for (int mr = 0; mr < MR; ++mr)
    #pragma unroll
    for (int ct = 0; ct < NT; ++ct) acc[mr][ct] = (f32x4){0.f, 0.f, 0.f, 0.f};

  const bf16* arow[MR];
  #pragma unroll
  for (int mr = 0; mr < MR; ++mr)
    arow[mr] = A + (size_t)(tile * (16 * MR) + mr * 16 + r) * Astride + g * 8;

  __syncthreads();

  #pragma unroll
  for (int ks = 0; ks < KS; ++ks) {
    const int cur = ks & 1;
    short8 a[MR];
    #pragma unroll
    for (int mr = 0; mr < MR; ++mr) a[mr] = *(const short8*)(arow[mr] + ks * 32);
    short8 st[CH];
    if (ks + 1 < KS) {
      const short8* src = (const short8*)(Wf + (size_t)(ks + 1) * BSZ);
      #pragma unroll
      for (int c = 0; c < CH; ++c) st[c] = src[c * 256 + j];
    }
    const bf16* wb = bs[cur] + (size_t)l * 8;
    #pragma unroll
    for (int ct = 0; ct < NT; ++ct) {
      short8 b = *(const short8*)(wb + ct * 512);
      #pragma unroll
      for (int mr = 0; mr < MR; ++mr)
        acc[mr][ct] = __builtin_amdgcn_mfma_f32_16x16x32_bf16(a[mr], b, acc[mr][ct], 0, 0, 0);
    }
    if (ks + 1 < KS) {
      short8* dst = (short8*)bs[cur ^ 1];
      #pragma unroll
      for (int c = 0; c < CH; ++c) dst[c * 256 + j] = st[c];
    }
    __syncthreads();
  }

  #pragma unroll
  for (int mr = 0; mr < MR; ++mr) {
    #pragma unroll
    for (int ct = 0; ct < NT; ++ct) {
      const float bj = bias[ct * 16 + r];
      #pragma unroll
      for (int i = 0; i < 4; ++i) acc[mr][ct][i] += bj;
    }
  }

  if (MODE == 0 || MODE == 2 || MODE == 4) {
    #pragma unroll
    for (int mr = 0; mr < MR; ++mr)
      #pragma unroll
      for (int ct = 0; ct < NT; ++ct)
        #pragma unroll
        for (int i = 0; i < 4; ++i) {
          float v = acc[mr][ct][i];
          if (MODE == 0) v = fmaxf(v, 0.f);
          size_t off = (size_t)(tile * (16 * MR) + mr * 16 + g * 4 + i) * N + ct * 16 + r;
          if (MODE == 4) ((float*)Cout)[off] = v;
          else           ((bf16*)Cout)[off]  = __float2bfloat16(v);
        }
  } else {
    #pragma unroll
    for (int mr = 0; mr < MR; ++mr) {
      float s[4] = {0.f, 0.f, 0.f, 0.f};
      #pragma unroll
      for (int ct = 0; ct < NT; ++ct)
        #pragma unroll
        for (int i = 0; i < 4; ++i) s[i] += acc[mr][ct][i] * acc[mr][ct][i];
      #pragma unroll
      for (int off = 1; off < 16; off <<= 1) {
        #pragma unroll
        for (int i = 0; i < 4; ++i) s[i] += __shfl_xor(s[i], off);
      }
      float rn[4];
      #pragma unroll
      for (int i = 0; i < 4; ++i) rn[i] = 1.f / fmaxf(sqrtf(s[i]), 1e-12f);
      #pragma unroll
      for (int ct = 0; ct < NT; ++ct)
        #pragma unroll
        for (int i = 0; i < 4; ++i) {
          size_t off = (size_t)(tile * (16 * MR) + mr * 16 + g * 4 + i) * N + ct * 16 + r;
          float v = acc[mr][ct][i] * rn[i];
          if (MODE == 3) ((float*)Cout)[off] = v;
          else           ((bf16*)Cout)[off]  = __float2bfloat16(v);
        }
    }
  }
}

// ---------------------------------------------------------------------------
// Attention v8b: ONE USER PER WAVE — no LDS, no barriers; prefetch depth 2.
// 4 groups of 16 lanes split the rows (h = g, g+4, ...); in-group shfl
// dot-reduce; no-max softmax (|s|<0.1 by construction); group partials merged
// in-register via shfl_xor(16,32); g==0 lanes store 2x short8 (coalesced).
// ---------------------------------------------------------------------------
__global__ __launch_bounds__(256) void k_user_attn(
    const float* __restrict__ Qt,          // [NUSERS][TOW] fp32 (Wqk-folded)
    const int*   __restrict__ hist_idx,
    const int*   __restrict__ hist_len,
    const unsigned char* __restrict__ emb8,// [rows][TOW] fp8 e4m3 (normalized)
    bf16* __restrict__ fused)
{
  const int wid = threadIdx.x >> 6, lane = threadIdx.x & 63;
  const int u = blockIdx.x * 4 + wid;
  const int g = lane >> 4, r = lane & 15;
  const int nv = hist_len[u] + 1;          // 1..48 valid rows
  const int* uidx = hist_idx + (size_t)u * HLEN;

  const float* qp = Qt + (size_t)u * TOW + r * 16;
  f32x4 q0 = *(const f32x4*)(qp);
  f32x4 q1 = *(const f32x4*)(qp + 4);
  f32x4 q2 = *(const f32x4*)(qp + 8);
  f32x4 q3 = *(const f32x4*)(qp + 12);

  float l = 0.f;
  f32x4 O0 = (f32x4){0.f,0.f,0.f,0.f}, O1 = O0, O2 = O0, O3 = O0;

  uchar16 cur = (uchar16){0,0,0,0,0,0,0,0,0,0,0,0,0,0,0,0};
  uchar16 nxt = cur;
  if (g < nv)
    cur = *(const uchar16*)(emb8 + (size_t)uidx[g] * TOW + r * 16);
  if (g + 4 < nv)
    nxt = *(const uchar16*)(emb8 + (size_t)uidx[g + 4] * TOW + r * 16);

  for (int h = g; h < nv; h += 4) {
    const uchar16 e = cur;
    cur = nxt;
    if (h + 8 < nv)
      nxt = *(const uchar16*)(emb8 + (size_t)uidx[h + 8] * TOW + r * 16);
    float ef[16];
    #pragma unroll
    for (int i = 0; i < 16; ++i) ef[i] = e4m3f(e[i]);

    float sc = q0.x*ef[0] + q0.y*ef[1] + q0.z*ef[2] + q0.w*ef[3]
             + q1.x*ef[4] + q1.y*ef[5] + q1.z*ef[6] + q1.w*ef[7]
             + q2.x*ef[8] + q2.y*ef[9] + q2.z*ef[10]+ q2.w*ef[11]
             + q3.x*ef[12]+ q3.y*ef[13]+ q3.z*ef[14]+ q3.w*ef[15];
    // reduce within the 16-lane group (xor 1,2,4,8 stay in-group)
    #pragma unroll
    for (int off = 1; off < 16; off <<= 1) sc += __shfl_xor(sc, off);
    const float p = __expf(sc);
    l += p;
    O0.x += p*ef[0];  O0.y += p*ef[1];  O0.z += p*ef[2];  O0.w += p*ef[3];
    O1.x += p*ef[4];  O1.y += p*ef[5];  O1.z += p*ef[6];  O1.w += p*ef[7];
    O2.x += p*ef[8];  O2.y += p*ef[9];  O2.z += p*ef[10]; O2.w += p*ef[11];
    O3.x += p*ef[12]; O3.y += p*ef[13]; O3.z += p*ef[14]; O3.w += p*ef[15];
  }

  // merge the 4 group partials in-register (same dims, disjoint rows)
  #pragma unroll
  for (int off = 16; off < 64; off <<= 1) {
    l += __shfl_xor(l, off);
    #pragma unroll
    for (int i = 0; i < 4; ++i) {
      O0[i] += __shfl_xor(O0[i], off);
      O1[i] += __shfl_xor(O1[i], off);
      O2[i] += __shfl_xor(O2[i], off);
      O3[i] += __shfl_xor(O3[i], off);
    }
  }

  if (g == 0) {
    const float inv = 1.f / l;
    short8 o0, o1;
    #pragma unroll
    for (int i = 0; i < 4; ++i) {
      o0[i]     = f2bf(O0[i] * inv);
      o0[4 + i] = f2bf(O1[i] * inv);
      o1[i]     = f2bf(O2[i] * inv);
      o1[4 + i] = f2bf(O3[i] * inv);
    }
    bf16* dst = fused + (size_t)u * (GCN + TOW) + GCN + r * 16;
    *(short8*)dst       = o0;
    *(short8*)(dst + 8) = o1;
  }
}

// ---------------------------------------------------------------------------
extern "C" void kernel_launch(void* const* d_in, const int* in_sizes, int n_in,
                              void* d_out, int out_size, void* d_ws, size_t ws_size,
                              hipStream_t stream) {
  const float* item_feat = (const float*)d_in[0];
  const float* gcn_item  = (const float*)d_in[1];
  const float* gcn_user  = (const float*)d_in[2];
  const int*   hist_idx  = (const int*)d_in[3];
  const int*   hist_len  = (const int*)d_in[4];
  const float* Wi1 = (const float*)d_in[5];
  const float* bi1 = (const float*)d_in[6];
  const float* Wi2 = (const float*)d_in[7];
  const float* bi2 = (const float*)d_in[8];
  const float* Wq  = (const float*)d_in[9];
  const float* bq  = (const float*)d_in[10];
  const float* Wk  = (const float*)d_in[11];
  const float* bk  = (const float*)d_in[12];  // cancels in softmax
  const float* Wu1 = (const float*)d_in[13];
  const float* bu1 = (const float*)d_in[14];
  const float* Wu2 = (const float*)d_in[15];
  const float* bu2 = (const float*)d_in[16];
  (void)bk;

  char* ws = (char*)d_ws;
  bf16*  Wi1p  = (bf16*)(ws + 0);            // 81,920 B
  unsigned char* Wi2p8 = (unsigned char*)(ws + 81920);  // 65,536 -> 147,456
  bf16*  Wu1p  = (bf16*)(ws + 147456);       // 196,608 -> 344,064
  bf16*  Wu2p  = (bf16*)(ws + 344064);       // 131,072 -> 475,136
  bf16*  Wqkp  = (bf16*)(ws + 475136);       // 65,536 -> 540,672
  float* bqt   = (float*)(ws + 540672);      // 1,024 -> 541,696
  float* Qt    = (float*)(ws + 541696);      // 16,777,216 -> 17,318,912
  unsigned char* h8   = (unsigned char*)(ws + 17318912); // 25,624,576 -> 42,943,488
  unsigned char* emb8 = (unsigned char*)(ws + 42943488); // 25,624,576 -> 68,568,064
  bf16*  fusedA   = (bf16*)(ws + 68568064);  // 12,582,912 -> 81,150,976
  bf16*  hu_buf   = (bf16*)(ws + 81150976);  // 8,388,608 -> 89,539,584

  // ---- fused prep (one launch) ----
  k_prep_all<<<9377, 256, 0, stream>>>(Wi1, Wi2, Wu1, Wu2, Wq, Wk, bq, gcn_user,
                                       Wi1p, Wi2p8, Wu1p, Wu2p, Wqkp, bqt, fusedA);

  // ---- item tower ----
  const int i128 = (NITEMS + 127) / 128;     // 782 (128-row tiles)
  k_item_g1<<<512, 512, 0, stream>>>(item_feat, gcn_item, Wi1p, Wi1, bi1, h8, i128);
  k_gemm2_f8<<<512, 512, 0, stream>>>(h8, Wi2p8, bi2, emb8, i128);

  // ---- user tower ----
  const int utiles = NUSERS / 32;            // 512
  const int ublk = utiles / 4;               // 128
  k_gemm<4, 16, 4, 2><<<ublk, 256, 0, stream>>>(fusedA, Wqkp, bqt, Qt, utiles, 384);
  k_user_attn<<<NUSERS / 4, 256, 0, stream>>>(Qt, hist_idx, hist_len, emb8, fusedA);
  k_gemm<12, 16, 0, 2><<<ublk, 256, 0, stream>>>(fusedA, Wu1p, bu1, hu_buf, utiles, 384);
  k_gemm<8, 16, 3, 2><<<ublk, 256, 0, stream>>>(hu_buf, Wu2p, bu2, (float*)d_out, utiles, 256);
}